// Round 4
// baseline (23359.055 us; speedup 1.0000x reference)
//
#include <hip/hip_runtime.h>
#include <float.h>
#include <stdint.h>

// VectorQuantizer R10: R8 base (proven 575us GEMM) + two measured fixes:
//  - T3 minimum 2-phase: double-buffered LDS (64KB, keeps 2 blocks/CU);
//    next chunk's 8 gload_lds issued BEFORE compute, single __syncthreads
//    per chunk AFTER compute -> load latency hides under ~460cyc of MFMA.
//  - T1 XCD-bijective swizzle (2048 blocks %8==0), ni-fastest per XCD ->
//    each XCD re-reads only 8 A-strips (1MB) from its own L2.
//  - A pre-converted (inp_conv), all four tiles via global_load_lds(16B)
//    with source-octet swizzle (0 bank conflicts). Accumulation order,
//    slot partition, epilogue: R8 verbatim -> numerics bit-identical.
//  - ws_size checked; falls back to R6-style in-kernel-convert GEMM.
// d_out = [quantized 16777216 f32][loss 1][indices 65536] ; scratch reuse:
//   pmin2 = 64 slots x float2 x 65536 rows (33.5MB), pidx 16.8MB
// d_ws floats: esq[0,4096) | fcount@4097 | flags@4100 | idx_final@69636 |
//   loss_part@135172 | emb_hi@151556 | emb_lo@675844 | a_hi@1200384 |
//   a_lo@9588992 (end 17977600 floats = 71.9MB; fallback needs only 4.8MB)

#define DDIM 256
#define KCODES 4096
#define NROWS 65536
#define QSIZE 16777216
#define NSLOT 64
#define NLBLK 16384
#define GAP_THRESH 0.02f

#define O_FCOUNT 4097
#define O_FLAGS 4100
#define O_IDXF 69636
#define O_LPART 135172
#define O_EMBH 151556
#define O_EMBL 675844
#define O_AH 1200384
#define O_AL 9588992
#define WS_NEED_FLOATS 17977600ull

typedef short bf16x8 __attribute__((ext_vector_type(8)));
typedef float f32x4 __attribute__((ext_vector_type(4)));

__device__ __forceinline__ void gload_lds16(const void* g, void* l) {
    __builtin_amdgcn_global_load_lds(
        (const __attribute__((address_space(1))) void*)g,
        (__attribute__((address_space(3))) void*)l, 16, 0, 0);
}

// ---- esq + emb hi/lo conversion + init (one pass over emb) ----
__global__ __launch_bounds__(64) void esq_conv(const float* __restrict__ emb,
                                               float* __restrict__ ws,
                                               short* __restrict__ eh,
                                               short* __restrict__ el) {
    int c = blockIdx.x, l = threadIdx.x;
    const float4* e4 = (const float4*)(emb + (size_t)c * DDIM);
    float4 v = e4[l];
    float s = v.x * v.x + v.y * v.y + v.z * v.z + v.w * v.w;
    float f[4] = {v.x, v.y, v.z, v.w};
    uint32_t hu[4], lu[4];
#pragma unroll
    for (int k = 0; k < 4; ++k) {
        uint32_t u = __float_as_uint(f[k]);
        uint32_t h = u & 0xFFFF0000u;
        hu[k] = h;
        lu[k] = __float_as_uint(f[k] - __uint_as_float(h));
    }
    uint2 hv, lv;
    hv.x = __builtin_amdgcn_perm(hu[1], hu[0], 0x07060302u);
    hv.y = __builtin_amdgcn_perm(hu[3], hu[2], 0x07060302u);
    lv.x = __builtin_amdgcn_perm(lu[1], lu[0], 0x07060302u);
    lv.y = __builtin_amdgcn_perm(lu[3], lu[2], 0x07060302u);
    *(uint2*)&eh[(size_t)c * DDIM + l * 4] = hv;
    *(uint2*)&el[(size_t)c * DDIM + l * 4] = lv;
#pragma unroll
    for (int off = 32; off >= 1; off >>= 1) s += __shfl_down(s, off);
    if (l == 0) ws[c] = s;
    if (c == 0 && l == 0) ((int*)ws)[O_FCOUNT] = 0;
}

// split fp32 -> (hi bf16, lo bf16), pack 8 elems, write 16B hi + 16B lo
__device__ __forceinline__ void conv8(float4 a, float4 b,
                                      short* __restrict__ dh,
                                      short* __restrict__ dl) {
    float f[8] = {a.x, a.y, a.z, a.w, b.x, b.y, b.z, b.w};
    uint32_t hu[8], lu[8];
#pragma unroll
    for (int k = 0; k < 8; ++k) {
        uint32_t u = __float_as_uint(f[k]);
        uint32_t h = u & 0xFFFF0000u;
        hu[k] = h;
        lu[k] = __float_as_uint(f[k] - __uint_as_float(h));
    }
    uint4 hv, lv;
    hv.x = __builtin_amdgcn_perm(hu[1], hu[0], 0x07060302u);
    hv.y = __builtin_amdgcn_perm(hu[3], hu[2], 0x07060302u);
    hv.z = __builtin_amdgcn_perm(hu[5], hu[4], 0x07060302u);
    hv.w = __builtin_amdgcn_perm(hu[7], hu[6], 0x07060302u);
    lv.x = __builtin_amdgcn_perm(lu[1], lu[0], 0x07060302u);
    lv.y = __builtin_amdgcn_perm(lu[3], lu[2], 0x07060302u);
    lv.z = __builtin_amdgcn_perm(lu[5], lu[4], 0x07060302u);
    lv.w = __builtin_amdgcn_perm(lu[7], lu[6], 0x07060302u);
    *(uint4*)dh = hv;
    *(uint4*)dl = lv;
}

__device__ __forceinline__ void stage8(const float* __restrict__ p,
                                       short* __restrict__ dh,
                                       short* __restrict__ dl) {
    float4 a = *(const float4*)p;
    float4 b = *(const float4*)(p + 4);
    conv8(a, b, dh, dl);
}

// ---- A pre-conversion: inp fp32 -> bf16 hi/lo (memory-bound, ~25us) ----
__global__ __launch_bounds__(256) void inp_conv(const float* __restrict__ inp,
                                                short* __restrict__ ahg,
                                                short* __restrict__ alg) {
    size_t g = (size_t)blockIdx.x * 256 + threadIdx.x;  // granule of 8 elems
    const float* p = inp + g * 8;
    float4 a = *(const float4*)p;
    float4 b = *(const float4*)(p + 4);
    conv8(a, b, ahg + g * 8, alg + g * 8);
}

// ---- main GEMM: 128x128 tile, dbuf LDS, prefetch-before-compute ----
__global__ __launch_bounds__(256, 2) void vq_gemm(const short* __restrict__ ahg,
                                                  const short* __restrict__ alg,
                                                  const short* __restrict__ ehg,
                                                  const short* __restrict__ elg,
                                                  const float* __restrict__ esq,
                                                  float2* __restrict__ pmin2,
                                                  int* __restrict__ pidx) {
    // 4 matrices x 2 buffers x 8 KB = 64 KB -> 2 blocks/CU (128 of 160 KB)
    __shared__ __align__(16) short Ah[2][4096];
    __shared__ __align__(16) short Al[2][4096];
    __shared__ __align__(16) short Bh[2][4096];
    __shared__ __align__(16) short Bl[2][4096];

    const int t = threadIdx.x;
    // T1: XCD-bijective swizzle (2048 blocks % 8 == 0). XCD k gets wg range
    // [k*256,(k+1)*256): 8 mi-strips x 32 ni -> A working set 1MB in its L2.
    const int wg = (blockIdx.x & 7) * 256 + (blockIdx.x >> 3);
    const int mi = wg >> 5, ni = wg & 31;
    const size_t row0 = (size_t)mi * 128;
    const int col0 = ni * 128;
    const int lane = t & 63, wave = t >> 6;
    const int wm = wave >> 1, wn = wave & 1;
    const int n15 = lane & 15, quad = lane >> 4;
    const int swz = (n15 >> 1) & 3;

    // staging coords (granule = 8 elems = 16B): granules g=t and g=t+256
    // r = g>>2, c8 = g&3; source octet k = c8 ^ ((r>>1)&3); dest linear g*16B
    const int ar0 = t >> 2, ac0 = t & 3;
    const int ap0 = ac0 ^ ((ar0 >> 1) & 3);
    const int ar1 = (t + 256) >> 2;
    const int ap1 = ac0 ^ ((ar1 >> 1) & 3);   // == ap0 (r+64 -> same s)
    const short* asrc0h = ahg + (size_t)(row0 + ar0) * DDIM + ap0 * 8;
    const short* asrc0l = alg + (size_t)(row0 + ar0) * DDIM + ap0 * 8;
    const short* asrc1h = ahg + (size_t)(row0 + ar1) * DDIM + ap1 * 8;
    const short* asrc1l = alg + (size_t)(row0 + ar1) * DDIM + ap1 * 8;
    const short* bsrc0h = ehg + (size_t)(col0 + ar0) * DDIM + ap0 * 8;
    const short* bsrc0l = elg + (size_t)(col0 + ar0) * DDIM + ap0 * 8;
    const short* bsrc1h = ehg + (size_t)(col0 + ar1) * DDIM + ap1 * 8;
    const short* bsrc1l = elg + (size_t)(col0 + ar1) * DDIM + ap1 * 8;
    const int d0 = t * 8, d1 = (t + 256) * 8;  // linear LDS dests

    f32x4 acc[4][4];
#pragma unroll
    for (int i = 0; i < 4; ++i)
#pragma unroll
        for (int j = 0; j < 4; ++j) {
            acc[i][j][0] = 0.f; acc[i][j][1] = 0.f;
            acc[i][j][2] = 0.f; acc[i][j][3] = 0.f;
        }

    // ---- prologue: stage chunk 0 into buffer 0 ----
    gload_lds16(asrc0h, &Ah[0][d0]);
    gload_lds16(asrc0l, &Al[0][d0]);
    gload_lds16(asrc1h, &Ah[0][d1]);
    gload_lds16(asrc1l, &Al[0][d1]);
    gload_lds16(bsrc0h, &Bh[0][d0]);
    gload_lds16(bsrc0l, &Bl[0][d0]);
    gload_lds16(bsrc1h, &Bh[0][d1]);
    gload_lds16(bsrc1l, &Bl[0][d1]);
    __syncthreads();   // vmcnt(0) drain: chunk 0 visible

#pragma unroll
    for (int ch = 0; ch < 8; ++ch) {
        const int cur = ch & 1, nxt = cur ^ 1;

        // T3: issue next chunk's staging BEFORE compute; drained by the
        // chunk-end __syncthreads (~460cyc of MFMA later -> latency hidden).
        if (ch < 7) {
            const int nk = (ch + 1) * 32;
            gload_lds16(asrc0h + nk, &Ah[nxt][d0]);
            gload_lds16(asrc0l + nk, &Al[nxt][d0]);
            gload_lds16(asrc1h + nk, &Ah[nxt][d1]);
            gload_lds16(asrc1l + nk, &Al[nxt][d1]);
            gload_lds16(bsrc0h + nk, &Bh[nxt][d0]);
            gload_lds16(bsrc0l + nk, &Bl[nxt][d0]);
            gload_lds16(bsrc1h + nk, &Bh[nxt][d1]);
            gload_lds16(bsrc1l + nk, &Bl[nxt][d1]);
        }
        __builtin_amdgcn_sched_barrier(0);  // pin issue before compute

        bf16x8 ah[4], al[4];
#pragma unroll
        for (int i = 0; i < 4; ++i) {
            int off = (wm * 64 + i * 16 + n15) * 32 + ((quad ^ swz) * 8);
            ah[i] = *(const bf16x8*)&Ah[cur][off];
            al[i] = *(const bf16x8*)&Al[cur][off];
        }
#pragma unroll
        for (int j = 0; j < 4; ++j) {
            int boff = (wn * 64 + j * 16 + n15) * 32 + ((quad ^ swz) * 8);
            bf16x8 bh = *(const bf16x8*)&Bh[cur][boff];
            bf16x8 bl = *(const bf16x8*)&Bl[cur][boff];
#pragma unroll
            for (int i = 0; i < 4; ++i) {
                acc[i][j] = __builtin_amdgcn_mfma_f32_16x16x32_bf16(ah[i], bh, acc[i][j], 0, 0, 0);
                acc[i][j] = __builtin_amdgcn_mfma_f32_16x16x32_bf16(ah[i], bl, acc[i][j], 0, 0, 0);
                acc[i][j] = __builtin_amdgcn_mfma_f32_16x16x32_bf16(al[i], bh, acc[i][j], 0, 0, 0);
            }
        }
        // single correctness-bearing sync per chunk: drains next-chunk
        // gloads (vmcnt) + fences this chunk's LDS reads before overwrite.
        __syncthreads();
    }

    // ---- epilogue: per-wave top-2 over its 64 codes (R4 verbatim) ----
    float esqv[4];
#pragma unroll
    for (int j = 0; j < 4; ++j) esqv[j] = esq[col0 + wn * 64 + j * 16 + n15];

#pragma unroll
    for (int i = 0; i < 4; ++i) {
#pragma unroll
        for (int reg = 0; reg < 4; ++reg) {
            float m1 = FLT_MAX, m2 = FLT_MAX;
            int bi = 0;
#pragma unroll
            for (int j = 0; j < 4; ++j) {
                float d = esqv[j] - 2.0f * acc[i][j][reg];
                int code = col0 + wn * 64 + j * 16 + n15;
                if (d < m1) { m2 = m1; m1 = d; bi = code; }
                else if (d < m2) { m2 = d; }
            }
#pragma unroll
            for (int off = 1; off < 16; off <<= 1) {
                float om1 = __shfl_xor(m1, off);
                float om2 = __shfl_xor(m2, off);
                int obi = __shfl_xor(bi, off);
                bool take = (om1 < m1) || (om1 == m1 && obi < bi);
                if (take) { m2 = fminf(m1, om2); m1 = om1; bi = obi; }
                else      { m2 = fminf(om1, m2); }
            }
            if (n15 == 0) {
                int rg = (int)row0 + wm * 64 + i * 16 + quad * 4 + reg;
                int slot = ni * 2 + wn;
                pmin2[(size_t)slot * NROWS + rg] = make_float2(m1, m2);
                pidx[(size_t)slot * NROWS + rg] = bi;
            }
        }
    }
}

// ---- fallback GEMM (R6 verbatim): in-kernel A conversion, small ws ----
__global__ __launch_bounds__(256, 2) void vq_gemm_fb(const float* __restrict__ inp,
                                                     const short* __restrict__ ehg,
                                                     const short* __restrict__ elg,
                                                     const float* __restrict__ esq,
                                                     float2* __restrict__ pmin2,
                                                     int* __restrict__ pidx) {
    __shared__ __align__(16) short Ah[128 * 32];
    __shared__ __align__(16) short Al[128 * 32];
    __shared__ __align__(16) short Bh[128 * 32];
    __shared__ __align__(16) short Bl[128 * 32];

    const int t = threadIdx.x;
    const int mi = blockIdx.x >> 5, ni = blockIdx.x & 31;
    const size_t row0 = (size_t)mi * 128;
    const int col0 = ni * 128;
    const int lane = t & 63, wave = t >> 6;
    const int wm = wave >> 1, wn = wave & 1;
    const int n15 = lane & 15, quad = lane >> 4;
    const int swz = (n15 >> 1) & 3;

    const int ar0 = t >> 2, ac0 = t & 3;
    const int ap0 = ac0 ^ ((ar0 >> 1) & 3);
    const int ar1 = (t + 256) >> 2, ac1 = ac0;
    const int ap1 = ac1 ^ ((ar1 >> 1) & 3);
    const float* asrc0 = inp + (row0 + ar0) * DDIM + ac0 * 8;
    const float* asrc1 = inp + (row0 + ar1) * DDIM + ac1 * 8;
    short* adst0h = &Ah[ar0 * 32 + ap0 * 8];
    short* adst0l = &Al[ar0 * 32 + ap0 * 8];
    short* adst1h = &Ah[ar1 * 32 + ap1 * 8];
    short* adst1l = &Al[ar1 * 32 + ap1 * 8];
    const int br0 = ar0, bp0 = ac0, bk0 = bp0 ^ ((br0 >> 1) & 3);
    const int br1 = ar1, bp1 = ac1, bk1 = bp1 ^ ((br1 >> 1) & 3);
    const short* bsrc0h = ehg + (size_t)(col0 + br0) * DDIM + bk0 * 8;
    const short* bsrc0l = elg + (size_t)(col0 + br0) * DDIM + bk0 * 8;
    const short* bsrc1h = ehg + (size_t)(col0 + br1) * DDIM + bk1 * 8;
    const short* bsrc1l = elg + (size_t)(col0 + br1) * DDIM + bk1 * 8;

    f32x4 acc[4][4];
#pragma unroll
    for (int i = 0; i < 4; ++i)
#pragma unroll
        for (int j = 0; j < 4; ++j) {
            acc[i][j][0] = 0.f; acc[i][j][1] = 0.f;
            acc[i][j][2] = 0.f; acc[i][j][3] = 0.f;
        }

#pragma unroll
    for (int ch = 0; ch < 8; ++ch) {
        __syncthreads();
        gload_lds16(bsrc0h + ch * 32, &Bh[t * 8]);
        gload_lds16(bsrc0l + ch * 32, &Bl[t * 8]);
        gload_lds16(bsrc1h + ch * 32, &Bh[(t + 256) * 8]);
        gload_lds16(bsrc1l + ch * 32, &Bl[(t + 256) * 8]);
        stage8(asrc0 + ch * 32, adst0h, adst0l);
        stage8(asrc1 + ch * 32, adst1h, adst1l);
        __syncthreads();

        bf16x8 ah[4], al[4];
#pragma unroll
        for (int i = 0; i < 4; ++i) {
            int off = (wm * 64 + i * 16 + n15) * 32 + ((quad ^ swz) * 8);
            ah[i] = *(const bf16x8*)&Ah[off];
            al[i] = *(const bf16x8*)&Al[off];
        }
#pragma unroll
        for (int j = 0; j < 4; ++j) {
            int boff = (wn * 64 + j * 16 + n15) * 32 + ((quad ^ swz) * 8);
            bf16x8 bh = *(const bf16x8*)&Bh[boff];
            bf16x8 bl = *(const bf16x8*)&Bl[boff];
#pragma unroll
            for (int i = 0; i < 4; ++i) {
                acc[i][j] = __builtin_amdgcn_mfma_f32_16x16x32_bf16(ah[i], bh, acc[i][j], 0, 0, 0);
                acc[i][j] = __builtin_amdgcn_mfma_f32_16x16x32_bf16(ah[i], bl, acc[i][j], 0, 0, 0);
                acc[i][j] = __builtin_amdgcn_mfma_f32_16x16x32_bf16(al[i], bh, acc[i][j], 0, 0, 0);
            }
        }
    }

    float esqv[4];
#pragma unroll
    for (int j = 0; j < 4; ++j) esqv[j] = esq[col0 + wn * 64 + j * 16 + n15];

#pragma unroll
    for (int i = 0; i < 4; ++i) {
#pragma unroll
        for (int reg = 0; reg < 4; ++reg) {
            float m1 = FLT_MAX, m2 = FLT_MAX;
            int bi = 0;
#pragma unroll
            for (int j = 0; j < 4; ++j) {
                float d = esqv[j] - 2.0f * acc[i][j][reg];
                int code = col0 + wn * 64 + j * 16 + n15;
                if (d < m1) { m2 = m1; m1 = d; bi = code; }
                else if (d < m2) { m2 = d; }
            }
#pragma unroll
            for (int off = 1; off < 16; off <<= 1) {
                float om1 = __shfl_xor(m1, off);
                float om2 = __shfl_xor(m2, off);
                int obi = __shfl_xor(bi, off);
                bool take = (om1 < m1) || (om1 == m1 && obi < bi);
                if (take) { m2 = fminf(m1, om2); m1 = om1; bi = obi; }
                else      { m2 = fminf(om1, m2); }
            }
            if (n15 == 0) {
                int rg = (int)row0 + wm * 64 + i * 16 + quad * 4 + reg;
                int slot = ni * 2 + wn;
                pmin2[(size_t)slot * NROWS + rg] = make_float2(m1, m2);
                pidx[(size_t)slot * NROWS + rg] = bi;
            }
        }
    }
}

// ---- reduce 64 per-wave partials per row; flag near-ties ----
__global__ __launch_bounds__(256) void vq_reduce(const float2* __restrict__ pmin2,
                                                 const int* __restrict__ pidx,
                                                 int* __restrict__ idx_final,
                                                 int* __restrict__ flags,
                                                 int* __restrict__ fcount) {
    int row = blockIdx.x * 256 + threadIdx.x;
    float m1 = FLT_MAX, m2 = FLT_MAX;
    int bi = 0;
    for (int nb = 0; nb < NSLOT; ++nb) {
        float2 p = pmin2[(size_t)nb * NROWS + row];
        int pi = pidx[(size_t)nb * NROWS + row];
        if (p.x < m1) { m2 = fminf(m1, p.y); m1 = p.x; bi = pi; }
        else          { m2 = fminf(m2, p.x); }
    }
    idx_final[row] = bi;
    if (m2 - m1 < GAP_THRESH) {
        int s = atomicAdd(fcount, 1);
        flags[s] = row;
    }
}

// ---- fp32 recheck of flagged rows (exact R1 semantics) ----
__global__ __launch_bounds__(256) void vq_recheck(const float* __restrict__ inp,
                                                  const float* __restrict__ emb,
                                                  const float* __restrict__ esq,
                                                  const int* __restrict__ flags,
                                                  const int* __restrict__ fcount,
                                                  int* __restrict__ idx_final) {
    __shared__ float4 xs[64];
    __shared__ float sv[4];
    __shared__ int si[4];
    const int t = threadIdx.x;
    const int cnt = *fcount;
    for (int f = blockIdx.x; f < cnt; f += gridDim.x) {
        int row = flags[f];
        __syncthreads();
        if (t < 64) xs[t] = ((const float4*)inp)[(size_t)row * 64 + t];
        __syncthreads();
        float m1 = FLT_MAX;
        int bi = 0x7FFFFFFF;
        for (int cc = 0; cc < 16; ++cc) {
            int c = cc * 256 + t;
            const float4* e4 = (const float4*)emb + (size_t)c * 64;
            float dot = 0.f;
            for (int d4 = 0; d4 < 64; ++d4) {
                float4 e = e4[d4];
                float4 x = xs[d4];
                dot += e.x * x.x; dot += e.y * x.y;
                dot += e.z * x.z; dot += e.w * x.w;
            }
            float d = esq[c] - 2.0f * dot;
            if (d < m1 || (d == m1 && c < bi)) { m1 = d; bi = c; }
        }
#pragma unroll
        for (int off = 1; off < 64; off <<= 1) {
            float om = __shfl_xor(m1, off);
            int ob = __shfl_xor(bi, off);
            if (om < m1 || (om == m1 && ob < bi)) { m1 = om; bi = ob; }
        }
        if ((t & 63) == 0) { sv[t >> 6] = m1; si[t >> 6] = bi; }
        __syncthreads();
        if (t == 0) {
            for (int w = 1; w < 4; ++w)
                if (sv[w] < m1 || (sv[w] == m1 && si[w] < bi)) { m1 = sv[w]; bi = si[w]; }
            idx_final[row] = bi;
        }
    }
}

// ---- gather quantized, write indices, per-block loss partial ----
__global__ __launch_bounds__(256) void vq_gather(const float* __restrict__ inp,
                                                 const float* __restrict__ emb,
                                                 const int* __restrict__ idx_final,
                                                 float* __restrict__ out,
                                                 float* __restrict__ loss_part) {
    __shared__ float wsum[4];
    size_t gid = (size_t)blockIdx.x * 256 + threadIdx.x;
    int row = (int)(gid >> 6), c4 = (int)(gid & 63);
    int k = idx_final[row];
    float4 e = ((const float4*)emb)[(size_t)k * 64 + c4];
    float4 x = ((const float4*)inp)[gid];
    ((float4*)out)[gid] = e;
    float dx = e.x - x.x, dy = e.y - x.y, dz = e.z - x.z, dw = e.w - x.w;
    float ls = dx * dx + dy * dy + dz * dz + dw * dw;
#pragma unroll
    for (int off = 32; off >= 1; off >>= 1) ls += __shfl_down(ls, off);
    if ((threadIdx.x & 63) == 0) wsum[threadIdx.x >> 6] = ls;
    if (c4 == 0) out[(size_t)QSIZE + 1 + row] = (float)k;
    __syncthreads();
    if (threadIdx.x == 0)
        loss_part[blockIdx.x] = wsum[0] + wsum[1] + wsum[2] + wsum[3];
}

__global__ __launch_bounds__(256) void loss_kernel(const float* __restrict__ loss_part,
                                                   float* __restrict__ out) {
    __shared__ float sw[4];
    int t = threadIdx.x;
    float s = 0.0f;
    for (int i = t; i < NLBLK; i += 256) s += loss_part[i];
#pragma unroll
    for (int off = 32; off >= 1; off >>= 1) s += __shfl_down(s, off);
    if ((t & 63) == 0) sw[t >> 6] = s;
    __syncthreads();
    if (t == 0)
        out[QSIZE] = (sw[0] + sw[1] + sw[2] + sw[3]) * (1.0f / 16777216.0f);
}

extern "C" void kernel_launch(void* const* d_in, const int* in_sizes, int n_in,
                              void* d_out, int out_size, void* d_ws, size_t ws_size,
                              hipStream_t stream) {
    const float* inp = (const float*)d_in[0];
    const float* emb = (const float*)d_in[1];
    float* out = (float*)d_out;
    float* ws = (float*)d_ws;

    float* esq = ws;
    int* fcount = (int*)ws + O_FCOUNT;
    int* flags = (int*)ws + O_FLAGS;
    int* idx_final = (int*)ws + O_IDXF;
    float* loss_part = ws + O_LPART;
    short* eh = (short*)(ws + O_EMBH);
    short* el = (short*)(ws + O_EMBL);

    // partials in d_out's quantized region (overwritten by vq_gather)
    float2* pmin2 = (float2*)out;                 // [0, 8388608) floats
    int* pidx = (int*)out + 8388608;              // [8388608, 12582912)

    hipLaunchKernelGGL(esq_conv, dim3(KCODES), dim3(64), 0, stream, emb, ws, eh, el);

    if (ws_size >= WS_NEED_FLOATS * 4ull) {
        short* ah = (short*)(ws + O_AH);
        short* al = (short*)(ws + O_AL);
        hipLaunchKernelGGL(inp_conv, dim3(8192), dim3(256), 0, stream, inp, ah, al);
        hipLaunchKernelGGL(vq_gemm, dim3((NROWS / 128) * 32), dim3(256), 0, stream,
                           ah, al, eh, el, esq, pmin2, pidx);
    } else {
        hipLaunchKernelGGL(vq_gemm_fb, dim3((NROWS / 128) * 32), dim3(256), 0, stream,
                           inp, eh, el, esq, pmin2, pidx);
    }

    hipLaunchKernelGGL(vq_reduce, dim3(NROWS / 256), dim3(256), 0, stream,
                       pmin2, pidx, idx_final, flags, fcount);
    hipLaunchKernelGGL(vq_recheck, dim3(256), dim3(256), 0, stream,
                       inp, emb, esq, flags, fcount, idx_final);
    hipLaunchKernelGGL(vq_gather, dim3(NLBLK), dim3(256), 0, stream,
                       inp, emb, idx_final, out, loss_part);
    hipLaunchKernelGGL(loss_kernel, dim3(1), dim3(256), 0, stream, loss_part, out);
}

// Round 5
// 961.020 us; speedup vs baseline: 24.3065x; 24.3065x over previous
//
#include <hip/hip_runtime.h>
#include <float.h>
#include <stdint.h>

// VectorQuantizer R11: R10 with the XCD-swizzle bug fixed.
//  R10's swizzle was written for 2048 blocks but the grid is 16384 ->
//  non-bijective mapping left 77% of tiles uncomputed; stale pmin2 flagged
//  ~all rows and vq_recheck brute-forced the output (22.7ms). Correct
//  bijective mapping for 16384 blocks: wg = (b&7)*2048 + (b>>3).
//  Everything else identical to R10:
//  - T3 minimum 2-phase: double-buffered LDS (64KB, 2 blocks/CU); next
//    chunk's 8 gload_lds issued BEFORE compute, single __syncthreads per
//    chunk AFTER compute -> load latency hides under MFMA.
//  - A pre-converted (inp_conv), all four tiles via global_load_lds(16B)
//    with source-octet swizzle (0 bank conflicts). Accumulation order,
//    slot partition, epilogue: R8 verbatim -> numerics bit-identical.
//  - ws_size checked; falls back to R6-style in-kernel-convert GEMM.
// d_out = [quantized 16777216 f32][loss 1][indices 65536] ; scratch reuse:
//   pmin2 = 64 slots x float2 x 65536 rows (33.5MB), pidx 16.8MB
// d_ws floats: esq[0,4096) | fcount@4097 | flags@4100 | idx_final@69636 |
//   loss_part@135172 | emb_hi@151556 | emb_lo@675844 | a_hi@1200384 |
//   a_lo@9588992 (end 17977600 floats = 71.9MB; fallback needs only 4.8MB)

#define DDIM 256
#define KCODES 4096
#define NROWS 65536
#define QSIZE 16777216
#define NSLOT 64
#define NLBLK 16384
#define GAP_THRESH 0.02f

#define O_FCOUNT 4097
#define O_FLAGS 4100
#define O_IDXF 69636
#define O_LPART 135172
#define O_EMBH 151556
#define O_EMBL 675844
#define O_AH 1200384
#define O_AL 9588992
#define WS_NEED_FLOATS 17977600ull

typedef short bf16x8 __attribute__((ext_vector_type(8)));
typedef float f32x4 __attribute__((ext_vector_type(4)));

__device__ __forceinline__ void gload_lds16(const void* g, void* l) {
    __builtin_amdgcn_global_load_lds(
        (const __attribute__((address_space(1))) void*)g,
        (__attribute__((address_space(3))) void*)l, 16, 0, 0);
}

// ---- esq + emb hi/lo conversion + init (one pass over emb) ----
__global__ __launch_bounds__(64) void esq_conv(const float* __restrict__ emb,
                                               float* __restrict__ ws,
                                               short* __restrict__ eh,
                                               short* __restrict__ el) {
    int c = blockIdx.x, l = threadIdx.x;
    const float4* e4 = (const float4*)(emb + (size_t)c * DDIM);
    float4 v = e4[l];
    float s = v.x * v.x + v.y * v.y + v.z * v.z + v.w * v.w;
    float f[4] = {v.x, v.y, v.z, v.w};
    uint32_t hu[4], lu[4];
#pragma unroll
    for (int k = 0; k < 4; ++k) {
        uint32_t u = __float_as_uint(f[k]);
        uint32_t h = u & 0xFFFF0000u;
        hu[k] = h;
        lu[k] = __float_as_uint(f[k] - __uint_as_float(h));
    }
    uint2 hv, lv;
    hv.x = __builtin_amdgcn_perm(hu[1], hu[0], 0x07060302u);
    hv.y = __builtin_amdgcn_perm(hu[3], hu[2], 0x07060302u);
    lv.x = __builtin_amdgcn_perm(lu[1], lu[0], 0x07060302u);
    lv.y = __builtin_amdgcn_perm(lu[3], lu[2], 0x07060302u);
    *(uint2*)&eh[(size_t)c * DDIM + l * 4] = hv;
    *(uint2*)&el[(size_t)c * DDIM + l * 4] = lv;
#pragma unroll
    for (int off = 32; off >= 1; off >>= 1) s += __shfl_down(s, off);
    if (l == 0) ws[c] = s;
    if (c == 0 && l == 0) ((int*)ws)[O_FCOUNT] = 0;
}

// split fp32 -> (hi bf16, lo bf16), pack 8 elems, write 16B hi + 16B lo
__device__ __forceinline__ void conv8(float4 a, float4 b,
                                      short* __restrict__ dh,
                                      short* __restrict__ dl) {
    float f[8] = {a.x, a.y, a.z, a.w, b.x, b.y, b.z, b.w};
    uint32_t hu[8], lu[8];
#pragma unroll
    for (int k = 0; k < 8; ++k) {
        uint32_t u = __float_as_uint(f[k]);
        uint32_t h = u & 0xFFFF0000u;
        hu[k] = h;
        lu[k] = __float_as_uint(f[k] - __uint_as_float(h));
    }
    uint4 hv, lv;
    hv.x = __builtin_amdgcn_perm(hu[1], hu[0], 0x07060302u);
    hv.y = __builtin_amdgcn_perm(hu[3], hu[2], 0x07060302u);
    hv.z = __builtin_amdgcn_perm(hu[5], hu[4], 0x07060302u);
    hv.w = __builtin_amdgcn_perm(hu[7], hu[6], 0x07060302u);
    lv.x = __builtin_amdgcn_perm(lu[1], lu[0], 0x07060302u);
    lv.y = __builtin_amdgcn_perm(lu[3], lu[2], 0x07060302u);
    lv.z = __builtin_amdgcn_perm(lu[5], lu[4], 0x07060302u);
    lv.w = __builtin_amdgcn_perm(lu[7], lu[6], 0x07060302u);
    *(uint4*)dh = hv;
    *(uint4*)dl = lv;
}

__device__ __forceinline__ void stage8(const float* __restrict__ p,
                                       short* __restrict__ dh,
                                       short* __restrict__ dl) {
    float4 a = *(const float4*)p;
    float4 b = *(const float4*)(p + 4);
    conv8(a, b, dh, dl);
}

// ---- A pre-conversion: inp fp32 -> bf16 hi/lo (memory-bound, ~25us) ----
__global__ __launch_bounds__(256) void inp_conv(const float* __restrict__ inp,
                                                short* __restrict__ ahg,
                                                short* __restrict__ alg) {
    size_t g = (size_t)blockIdx.x * 256 + threadIdx.x;  // granule of 8 elems
    const float* p = inp + g * 8;
    float4 a = *(const float4*)p;
    float4 b = *(const float4*)(p + 4);
    conv8(a, b, ahg + g * 8, alg + g * 8);
}

// ---- main GEMM: 128x128 tile, dbuf LDS, prefetch-before-compute ----
__global__ __launch_bounds__(256, 2) void vq_gemm(const short* __restrict__ ahg,
                                                  const short* __restrict__ alg,
                                                  const short* __restrict__ ehg,
                                                  const short* __restrict__ elg,
                                                  const float* __restrict__ esq,
                                                  float2* __restrict__ pmin2,
                                                  int* __restrict__ pidx) {
    // 4 matrices x 2 buffers x 8 KB = 64 KB -> 2 blocks/CU (128 of 160 KB)
    __shared__ __align__(16) short Ah[2][4096];
    __shared__ __align__(16) short Al[2][4096];
    __shared__ __align__(16) short Bh[2][4096];
    __shared__ __align__(16) short Bl[2][4096];

    const int t = threadIdx.x;
    // T1: XCD-bijective swizzle for 16384 blocks (%8==0): XCD k gets the
    // contiguous wg range [k*2048,(k+1)*2048) = 64 mi-strips x 32 ni,
    // ni-fastest -> consecutive wgs on one XCD share an A-strip in its L2.
    const int wg = (blockIdx.x & 7) * 2048 + (blockIdx.x >> 3);
    const int mi = wg >> 5, ni = wg & 31;
    const size_t row0 = (size_t)mi * 128;
    const int col0 = ni * 128;
    const int lane = t & 63, wave = t >> 6;
    const int wm = wave >> 1, wn = wave & 1;
    const int n15 = lane & 15, quad = lane >> 4;
    const int swz = (n15 >> 1) & 3;

    // staging coords (granule = 8 elems = 16B): granules g=t and g=t+256
    // r = g>>2, c8 = g&3; source octet k = c8 ^ ((r>>1)&3); dest linear g*16B
    const int ar0 = t >> 2, ac0 = t & 3;
    const int ap0 = ac0 ^ ((ar0 >> 1) & 3);
    const int ar1 = (t + 256) >> 2;
    const int ap1 = ac0 ^ ((ar1 >> 1) & 3);   // == ap0 (r+64 -> same s)
    const short* asrc0h = ahg + (size_t)(row0 + ar0) * DDIM + ap0 * 8;
    const short* asrc0l = alg + (size_t)(row0 + ar0) * DDIM + ap0 * 8;
    const short* asrc1h = ahg + (size_t)(row0 + ar1) * DDIM + ap1 * 8;
    const short* asrc1l = alg + (size_t)(row0 + ar1) * DDIM + ap1 * 8;
    const short* bsrc0h = ehg + (size_t)(col0 + ar0) * DDIM + ap0 * 8;
    const short* bsrc0l = elg + (size_t)(col0 + ar0) * DDIM + ap0 * 8;
    const short* bsrc1h = ehg + (size_t)(col0 + ar1) * DDIM + ap1 * 8;
    const short* bsrc1l = elg + (size_t)(col0 + ar1) * DDIM + ap1 * 8;
    const int d0 = t * 8, d1 = (t + 256) * 8;  // linear LDS dests

    f32x4 acc[4][4];
#pragma unroll
    for (int i = 0; i < 4; ++i)
#pragma unroll
        for (int j = 0; j < 4; ++j) {
            acc[i][j][0] = 0.f; acc[i][j][1] = 0.f;
            acc[i][j][2] = 0.f; acc[i][j][3] = 0.f;
        }

    // ---- prologue: stage chunk 0 into buffer 0 ----
    gload_lds16(asrc0h, &Ah[0][d0]);
    gload_lds16(asrc0l, &Al[0][d0]);
    gload_lds16(asrc1h, &Ah[0][d1]);
    gload_lds16(asrc1l, &Al[0][d1]);
    gload_lds16(bsrc0h, &Bh[0][d0]);
    gload_lds16(bsrc0l, &Bl[0][d0]);
    gload_lds16(bsrc1h, &Bh[0][d1]);
    gload_lds16(bsrc1l, &Bl[0][d1]);
    __syncthreads();   // vmcnt(0) drain: chunk 0 visible

#pragma unroll
    for (int ch = 0; ch < 8; ++ch) {
        const int cur = ch & 1, nxt = cur ^ 1;

        // T3: issue next chunk's staging BEFORE compute; drained by the
        // chunk-end __syncthreads (~460cyc of MFMA later -> latency hidden).
        if (ch < 7) {
            const int nk = (ch + 1) * 32;
            gload_lds16(asrc0h + nk, &Ah[nxt][d0]);
            gload_lds16(asrc0l + nk, &Al[nxt][d0]);
            gload_lds16(asrc1h + nk, &Ah[nxt][d1]);
            gload_lds16(asrc1l + nk, &Al[nxt][d1]);
            gload_lds16(bsrc0h + nk, &Bh[nxt][d0]);
            gload_lds16(bsrc0l + nk, &Bl[nxt][d0]);
            gload_lds16(bsrc1h + nk, &Bh[nxt][d1]);
            gload_lds16(bsrc1l + nk, &Bl[nxt][d1]);
        }
        __builtin_amdgcn_sched_barrier(0);  // pin issue before compute

        bf16x8 ah[4], al[4];
#pragma unroll
        for (int i = 0; i < 4; ++i) {
            int off = (wm * 64 + i * 16 + n15) * 32 + ((quad ^ swz) * 8);
            ah[i] = *(const bf16x8*)&Ah[cur][off];
            al[i] = *(const bf16x8*)&Al[cur][off];
        }
#pragma unroll
        for (int j = 0; j < 4; ++j) {
            int boff = (wn * 64 + j * 16 + n15) * 32 + ((quad ^ swz) * 8);
            bf16x8 bh = *(const bf16x8*)&Bh[cur][boff];
            bf16x8 bl = *(const bf16x8*)&Bl[cur][boff];
#pragma unroll
            for (int i = 0; i < 4; ++i) {
                acc[i][j] = __builtin_amdgcn_mfma_f32_16x16x32_bf16(ah[i], bh, acc[i][j], 0, 0, 0);
                acc[i][j] = __builtin_amdgcn_mfma_f32_16x16x32_bf16(ah[i], bl, acc[i][j], 0, 0, 0);
                acc[i][j] = __builtin_amdgcn_mfma_f32_16x16x32_bf16(al[i], bh, acc[i][j], 0, 0, 0);
            }
        }
        // single correctness-bearing sync per chunk: drains next-chunk
        // gloads (vmcnt) + fences this chunk's LDS reads before overwrite.
        __syncthreads();
    }

    // ---- epilogue: per-wave top-2 over its 64 codes (R4 verbatim) ----
    float esqv[4];
#pragma unroll
    for (int j = 0; j < 4; ++j) esqv[j] = esq[col0 + wn * 64 + j * 16 + n15];

#pragma unroll
    for (int i = 0; i < 4; ++i) {
#pragma unroll
        for (int reg = 0; reg < 4; ++reg) {
            float m1 = FLT_MAX, m2 = FLT_MAX;
            int bi = 0;
#pragma unroll
            for (int j = 0; j < 4; ++j) {
                float d = esqv[j] - 2.0f * acc[i][j][reg];
                int code = col0 + wn * 64 + j * 16 + n15;
                if (d < m1) { m2 = m1; m1 = d; bi = code; }
                else if (d < m2) { m2 = d; }
            }
#pragma unroll
            for (int off = 1; off < 16; off <<= 1) {
                float om1 = __shfl_xor(m1, off);
                float om2 = __shfl_xor(m2, off);
                int obi = __shfl_xor(bi, off);
                bool take = (om1 < m1) || (om1 == m1 && obi < bi);
                if (take) { m2 = fminf(m1, om2); m1 = om1; bi = obi; }
                else      { m2 = fminf(om1, m2); }
            }
            if (n15 == 0) {
                int rg = (int)row0 + wm * 64 + i * 16 + quad * 4 + reg;
                int slot = ni * 2 + wn;
                pmin2[(size_t)slot * NROWS + rg] = make_float2(m1, m2);
                pidx[(size_t)slot * NROWS + rg] = bi;
            }
        }
    }
}

// ---- fallback GEMM (R6 verbatim): in-kernel A conversion, small ws ----
__global__ __launch_bounds__(256, 2) void vq_gemm_fb(const float* __restrict__ inp,
                                                     const short* __restrict__ ehg,
                                                     const short* __restrict__ elg,
                                                     const float* __restrict__ esq,
                                                     float2* __restrict__ pmin2,
                                                     int* __restrict__ pidx) {
    __shared__ __align__(16) short Ah[128 * 32];
    __shared__ __align__(16) short Al[128 * 32];
    __shared__ __align__(16) short Bh[128 * 32];
    __shared__ __align__(16) short Bl[128 * 32];

    const int t = threadIdx.x;
    const int mi = blockIdx.x >> 5, ni = blockIdx.x & 31;
    const size_t row0 = (size_t)mi * 128;
    const int col0 = ni * 128;
    const int lane = t & 63, wave = t >> 6;
    const int wm = wave >> 1, wn = wave & 1;
    const int n15 = lane & 15, quad = lane >> 4;
    const int swz = (n15 >> 1) & 3;

    const int ar0 = t >> 2, ac0 = t & 3;
    const int ap0 = ac0 ^ ((ar0 >> 1) & 3);
    const int ar1 = (t + 256) >> 2, ac1 = ac0;
    const int ap1 = ac1 ^ ((ar1 >> 1) & 3);
    const float* asrc0 = inp + (row0 + ar0) * DDIM + ac0 * 8;
    const float* asrc1 = inp + (row0 + ar1) * DDIM + ac1 * 8;
    short* adst0h = &Ah[ar0 * 32 + ap0 * 8];
    short* adst0l = &Al[ar0 * 32 + ap0 * 8];
    short* adst1h = &Ah[ar1 * 32 + ap1 * 8];
    short* adst1l = &Al[ar1 * 32 + ap1 * 8];
    const int br0 = ar0, bp0 = ac0, bk0 = bp0 ^ ((br0 >> 1) & 3);
    const int br1 = ar1, bp1 = ac1, bk1 = bp1 ^ ((br1 >> 1) & 3);
    const short* bsrc0h = ehg + (size_t)(col0 + br0) * DDIM + bk0 * 8;
    const short* bsrc0l = elg + (size_t)(col0 + br0) * DDIM + bk0 * 8;
    const short* bsrc1h = ehg + (size_t)(col0 + br1) * DDIM + bk1 * 8;
    const short* bsrc1l = elg + (size_t)(col0 + br1) * DDIM + bk1 * 8;

    f32x4 acc[4][4];
#pragma unroll
    for (int i = 0; i < 4; ++i)
#pragma unroll
        for (int j = 0; j < 4; ++j) {
            acc[i][j][0] = 0.f; acc[i][j][1] = 0.f;
            acc[i][j][2] = 0.f; acc[i][j][3] = 0.f;
        }

#pragma unroll
    for (int ch = 0; ch < 8; ++ch) {
        __syncthreads();
        gload_lds16(bsrc0h + ch * 32, &Bh[t * 8]);
        gload_lds16(bsrc0l + ch * 32, &Bl[t * 8]);
        gload_lds16(bsrc1h + ch * 32, &Bh[(t + 256) * 8]);
        gload_lds16(bsrc1l + ch * 32, &Bl[(t + 256) * 8]);
        stage8(asrc0 + ch * 32, adst0h, adst0l);
        stage8(asrc1 + ch * 32, adst1h, adst1l);
        __syncthreads();

        bf16x8 ah[4], al[4];
#pragma unroll
        for (int i = 0; i < 4; ++i) {
            int off = (wm * 64 + i * 16 + n15) * 32 + ((quad ^ swz) * 8);
            ah[i] = *(const bf16x8*)&Ah[off];
            al[i] = *(const bf16x8*)&Al[off];
        }
#pragma unroll
        for (int j = 0; j < 4; ++j) {
            int boff = (wn * 64 + j * 16 + n15) * 32 + ((quad ^ swz) * 8);
            bf16x8 bh = *(const bf16x8*)&Bh[boff];
            bf16x8 bl = *(const bf16x8*)&Bl[boff];
#pragma unroll
            for (int i = 0; i < 4; ++i) {
                acc[i][j] = __builtin_amdgcn_mfma_f32_16x16x32_bf16(ah[i], bh, acc[i][j], 0, 0, 0);
                acc[i][j] = __builtin_amdgcn_mfma_f32_16x16x32_bf16(ah[i], bl, acc[i][j], 0, 0, 0);
                acc[i][j] = __builtin_amdgcn_mfma_f32_16x16x32_bf16(al[i], bh, acc[i][j], 0, 0, 0);
            }
        }
    }

    float esqv[4];
#pragma unroll
    for (int j = 0; j < 4; ++j) esqv[j] = esq[col0 + wn * 64 + j * 16 + n15];

#pragma unroll
    for (int i = 0; i < 4; ++i) {
#pragma unroll
        for (int reg = 0; reg < 4; ++reg) {
            float m1 = FLT_MAX, m2 = FLT_MAX;
            int bi = 0;
#pragma unroll
            for (int j = 0; j < 4; ++j) {
                float d = esqv[j] - 2.0f * acc[i][j][reg];
                int code = col0 + wn * 64 + j * 16 + n15;
                if (d < m1) { m2 = m1; m1 = d; bi = code; }
                else if (d < m2) { m2 = d; }
            }
#pragma unroll
            for (int off = 1; off < 16; off <<= 1) {
                float om1 = __shfl_xor(m1, off);
                float om2 = __shfl_xor(m2, off);
                int obi = __shfl_xor(bi, off);
                bool take = (om1 < m1) || (om1 == m1 && obi < bi);
                if (take) { m2 = fminf(m1, om2); m1 = om1; bi = obi; }
                else      { m2 = fminf(om1, m2); }
            }
            if (n15 == 0) {
                int rg = (int)row0 + wm * 64 + i * 16 + quad * 4 + reg;
                int slot = ni * 2 + wn;
                pmin2[(size_t)slot * NROWS + rg] = make_float2(m1, m2);
                pidx[(size_t)slot * NROWS + rg] = bi;
            }
        }
    }
}

// ---- reduce 64 per-wave partials per row; flag near-ties ----
__global__ __launch_bounds__(256) void vq_reduce(const float2* __restrict__ pmin2,
                                                 const int* __restrict__ pidx,
                                                 int* __restrict__ idx_final,
                                                 int* __restrict__ flags,
                                                 int* __restrict__ fcount) {
    int row = blockIdx.x * 256 + threadIdx.x;
    float m1 = FLT_MAX, m2 = FLT_MAX;
    int bi = 0;
    for (int nb = 0; nb < NSLOT; ++nb) {
        float2 p = pmin2[(size_t)nb * NROWS + row];
        int pi = pidx[(size_t)nb * NROWS + row];
        if (p.x < m1) { m2 = fminf(m1, p.y); m1 = p.x; bi = pi; }
        else          { m2 = fminf(m2, p.x); }
    }
    idx_final[row] = bi;
    if (m2 - m1 < GAP_THRESH) {
        int s = atomicAdd(fcount, 1);
        flags[s] = row;
    }
}

// ---- fp32 recheck of flagged rows (exact R1 semantics) ----
__global__ __launch_bounds__(256) void vq_recheck(const float* __restrict__ inp,
                                                  const float* __restrict__ emb,
                                                  const float* __restrict__ esq,
                                                  const int* __restrict__ flags,
                                                  const int* __restrict__ fcount,
                                                  int* __restrict__ idx_final) {
    __shared__ float4 xs[64];
    __shared__ float sv[4];
    __shared__ int si[4];
    const int t = threadIdx.x;
    const int cnt = *fcount;
    for (int f = blockIdx.x; f < cnt; f += gridDim.x) {
        int row = flags[f];
        __syncthreads();
        if (t < 64) xs[t] = ((const float4*)inp)[(size_t)row * 64 + t];
        __syncthreads();
        float m1 = FLT_MAX;
        int bi = 0x7FFFFFFF;
        for (int cc = 0; cc < 16; ++cc) {
            int c = cc * 256 + t;
            const float4* e4 = (const float4*)emb + (size_t)c * 64;
            float dot = 0.f;
            for (int d4 = 0; d4 < 64; ++d4) {
                float4 e = e4[d4];
                float4 x = xs[d4];
                dot += e.x * x.x; dot += e.y * x.y;
                dot += e.z * x.z; dot += e.w * x.w;
            }
            float d = esq[c] - 2.0f * dot;
            if (d < m1 || (d == m1 && c < bi)) { m1 = d; bi = c; }
        }
#pragma unroll
        for (int off = 1; off < 64; off <<= 1) {
            float om = __shfl_xor(m1, off);
            int ob = __shfl_xor(bi, off);
            if (om < m1 || (om == m1 && ob < bi)) { m1 = om; bi = ob; }
        }
        if ((t & 63) == 0) { sv[t >> 6] = m1; si[t >> 6] = bi; }
        __syncthreads();
        if (t == 0) {
            for (int w = 1; w < 4; ++w)
                if (sv[w] < m1 || (sv[w] == m1 && si[w] < bi)) { m1 = sv[w]; bi = si[w]; }
            idx_final[row] = bi;
        }
    }
}

// ---- gather quantized, write indices, per-block loss partial ----
__global__ __launch_bounds__(256) void vq_gather(const float* __restrict__ inp,
                                                 const float* __restrict__ emb,
                                                 const int* __restrict__ idx_final,
                                                 float* __restrict__ out,
                                                 float* __restrict__ loss_part) {
    __shared__ float wsum[4];
    size_t gid = (size_t)blockIdx.x * 256 + threadIdx.x;
    int row = (int)(gid >> 6), c4 = (int)(gid & 63);
    int k = idx_final[row];
    float4 e = ((const float4*)emb)[(size_t)k * 64 + c4];
    float4 x = ((const float4*)inp)[gid];
    ((float4*)out)[gid] = e;
    float dx = e.x - x.x, dy = e.y - x.y, dz = e.z - x.z, dw = e.w - x.w;
    float ls = dx * dx + dy * dy + dz * dz + dw * dw;
#pragma unroll
    for (int off = 32; off >= 1; off >>= 1) ls += __shfl_down(ls, off);
    if ((threadIdx.x & 63) == 0) wsum[threadIdx.x >> 6] = ls;
    if (c4 == 0) out[(size_t)QSIZE + 1 + row] = (float)k;
    __syncthreads();
    if (threadIdx.x == 0)
        loss_part[blockIdx.x] = wsum[0] + wsum[1] + wsum[2] + wsum[3];
}

__global__ __launch_bounds__(256) void loss_kernel(const float* __restrict__ loss_part,
                                                   float* __restrict__ out) {
    __shared__ float sw[4];
    int t = threadIdx.x;
    float s = 0.0f;
    for (int i = t; i < NLBLK; i += 256) s += loss_part[i];
#pragma unroll
    for (int off = 32; off >= 1; off >>= 1) s += __shfl_down(s, off);
    if ((t & 63) == 0) sw[t >> 6] = s;
    __syncthreads();
    if (t == 0)
        out[QSIZE] = (sw[0] + sw[1] + sw[2] + sw[3]) * (1.0f / 16777216.0f);
}

extern "C" void kernel_launch(void* const* d_in, const int* in_sizes, int n_in,
                              void* d_out, int out_size, void* d_ws, size_t ws_size,
                              hipStream_t stream) {
    const float* inp = (const float*)d_in[0];
    const float* emb = (const float*)d_in[1];
    float* out = (float*)d_out;
    float* ws = (float*)d_ws;

    float* esq = ws;
    int* fcount = (int*)ws + O_FCOUNT;
    int* flags = (int*)ws + O_FLAGS;
    int* idx_final = (int*)ws + O_IDXF;
    float* loss_part = ws + O_LPART;
    short* eh = (short*)(ws + O_EMBH);
    short* el = (short*)(ws + O_EMBL);

    // partials in d_out's quantized region (overwritten by vq_gather)
    float2* pmin2 = (float2*)out;                 // [0, 8388608) floats
    int* pidx = (int*)out + 8388608;              // [8388608, 12582912)

    hipLaunchKernelGGL(esq_conv, dim3(KCODES), dim3(64), 0, stream, emb, ws, eh, el);

    if (ws_size >= WS_NEED_FLOATS * 4ull) {
        short* ah = (short*)(ws + O_AH);
        short* al = (short*)(ws + O_AL);
        hipLaunchKernelGGL(inp_conv, dim3(8192), dim3(256), 0, stream, inp, ah, al);
        hipLaunchKernelGGL(vq_gemm, dim3((NROWS / 128) * 32), dim3(256), 0, stream,
                           ah, al, eh, el, esq, pmin2, pidx);
    } else {
        hipLaunchKernelGGL(vq_gemm_fb, dim3((NROWS / 128) * 32), dim3(256), 0, stream,
                           inp, eh, el, esq, pmin2, pidx);
    }

    hipLaunchKernelGGL(vq_reduce, dim3(NROWS / 256), dim3(256), 0, stream,
                       pmin2, pidx, idx_final, flags, fcount);
    hipLaunchKernelGGL(vq_recheck, dim3(256), dim3(256), 0, stream,
                       inp, emb, esq, flags, fcount, idx_final);
    hipLaunchKernelGGL(vq_gather, dim3(NLBLK), dim3(256), 0, stream,
                       inp, emb, idx_final, out, loss_part);
    hipLaunchKernelGGL(loss_kernel, dim3(1), dim3(256), 0, stream, loss_part, out);
}

// Round 6
// 776.464 us; speedup vs baseline: 30.0839x; 1.2377x over previous
//
#include <hip/hip_runtime.h>
#include <float.h>
#include <stdint.h>

// VectorQuantizer R12: R8 verbatim (proven 575us GEMM, best total 795.8us)
// + ONE change: __launch_bounds__(256, 4) on vq_gemm.
//  Rationale: R8 occupancy 33% = 2.7 blocks/CU; limiter is unified regs
//  (64 AGPR acc + 68 VGPR = 132 -> 3 waves/SIMD). Capping at 4 waves/EU
//  forces VGPR<=64 -> 128 total -> 4 blocks/CU resident -> more implicit
//  overlap of the per-chunk vmcnt drain (m114 mechanism).
//  R11's bundled changes (XCD swizzle, 64KB dbuf) both measured negative
//  (FETCH 264->530MB B-thrash; occupancy 33->23%) and are reverted.
// d_out = [quantized 16777216 f32][loss 1][indices 65536] ; scratch reuse:
//   pmin2 = 64 slots x float2 x 65536 rows (33.5MB), pidx 16.8MB
// d_ws floats: esq[0,4096) | fcount@4097 | flags@4100 | idx_final@69636 |
//   loss_part@135172 | emb_hi@151556 | emb_lo@675844 | a_hi@1200384 |
//   a_lo@9588992 (end 17977600 floats = 71.9MB; fallback needs only 4.8MB)

#define DDIM 256
#define KCODES 4096
#define NROWS 65536
#define QSIZE 16777216
#define NSLOT 64
#define NLBLK 16384
#define GAP_THRESH 0.02f

#define O_FCOUNT 4097
#define O_FLAGS 4100
#define O_IDXF 69636
#define O_LPART 135172
#define O_EMBH 151556
#define O_EMBL 675844
#define O_AH 1200384
#define O_AL 9588992
#define WS_NEED_FLOATS 17977600ull

typedef short bf16x8 __attribute__((ext_vector_type(8)));
typedef float f32x4 __attribute__((ext_vector_type(4)));

__device__ __forceinline__ void gload_lds16(const void* g, void* l) {
    __builtin_amdgcn_global_load_lds(
        (const __attribute__((address_space(1))) void*)g,
        (__attribute__((address_space(3))) void*)l, 16, 0, 0);
}

// ---- esq + emb hi/lo conversion + init (one pass over emb) ----
__global__ __launch_bounds__(64) void esq_conv(const float* __restrict__ emb,
                                               float* __restrict__ ws,
                                               short* __restrict__ eh,
                                               short* __restrict__ el) {
    int c = blockIdx.x, l = threadIdx.x;
    const float4* e4 = (const float4*)(emb + (size_t)c * DDIM);
    float4 v = e4[l];
    float s = v.x * v.x + v.y * v.y + v.z * v.z + v.w * v.w;
    float f[4] = {v.x, v.y, v.z, v.w};
    uint32_t hu[4], lu[4];
#pragma unroll
    for (int k = 0; k < 4; ++k) {
        uint32_t u = __float_as_uint(f[k]);
        uint32_t h = u & 0xFFFF0000u;
        hu[k] = h;
        lu[k] = __float_as_uint(f[k] - __uint_as_float(h));
    }
    uint2 hv, lv;
    hv.x = __builtin_amdgcn_perm(hu[1], hu[0], 0x07060302u);
    hv.y = __builtin_amdgcn_perm(hu[3], hu[2], 0x07060302u);
    lv.x = __builtin_amdgcn_perm(lu[1], lu[0], 0x07060302u);
    lv.y = __builtin_amdgcn_perm(lu[3], lu[2], 0x07060302u);
    *(uint2*)&eh[(size_t)c * DDIM + l * 4] = hv;
    *(uint2*)&el[(size_t)c * DDIM + l * 4] = lv;
#pragma unroll
    for (int off = 32; off >= 1; off >>= 1) s += __shfl_down(s, off);
    if (l == 0) ws[c] = s;
    if (c == 0 && l == 0) ((int*)ws)[O_FCOUNT] = 0;
}

// split fp32 -> (hi bf16, lo bf16), pack 8 elems, write 16B hi + 16B lo
__device__ __forceinline__ void conv8(float4 a, float4 b,
                                      short* __restrict__ dh,
                                      short* __restrict__ dl) {
    float f[8] = {a.x, a.y, a.z, a.w, b.x, b.y, b.z, b.w};
    uint32_t hu[8], lu[8];
#pragma unroll
    for (int k = 0; k < 8; ++k) {
        uint32_t u = __float_as_uint(f[k]);
        uint32_t h = u & 0xFFFF0000u;
        hu[k] = h;
        lu[k] = __float_as_uint(f[k] - __uint_as_float(h));
    }
    uint4 hv, lv;
    hv.x = __builtin_amdgcn_perm(hu[1], hu[0], 0x07060302u);
    hv.y = __builtin_amdgcn_perm(hu[3], hu[2], 0x07060302u);
    hv.z = __builtin_amdgcn_perm(hu[5], hu[4], 0x07060302u);
    hv.w = __builtin_amdgcn_perm(hu[7], hu[6], 0x07060302u);
    lv.x = __builtin_amdgcn_perm(lu[1], lu[0], 0x07060302u);
    lv.y = __builtin_amdgcn_perm(lu[3], lu[2], 0x07060302u);
    lv.z = __builtin_amdgcn_perm(lu[5], lu[4], 0x07060302u);
    lv.w = __builtin_amdgcn_perm(lu[7], lu[6], 0x07060302u);
    *(uint4*)dh = hv;
    *(uint4*)dl = lv;
}

__device__ __forceinline__ void stage8(const float* __restrict__ p,
                                       short* __restrict__ dh,
                                       short* __restrict__ dl) {
    float4 a = *(const float4*)p;
    float4 b = *(const float4*)(p + 4);
    conv8(a, b, dh, dl);
}

// ---- A pre-conversion: inp fp32 -> bf16 hi/lo (memory-bound, ~25us) ----
__global__ __launch_bounds__(256) void inp_conv(const float* __restrict__ inp,
                                                short* __restrict__ ahg,
                                                short* __restrict__ alg) {
    size_t g = (size_t)blockIdx.x * 256 + threadIdx.x;  // granule of 8 elems
    const float* p = inp + g * 8;
    float4 a = *(const float4*)p;
    float4 b = *(const float4*)(p + 4);
    conv8(a, b, ahg + g * 8, alg + g * 8);
}

// ---- main GEMM: 128x128 tile, 8 chunks of 32 dims, 3 bf16 passes ----
// All four tiles via gload_lds: dest linear (slot c8 of row r), source
// octet k = c8 ^ ((r>>1)&3)  ->  physical slot p holds logical octet p^s,
// identical layout to R6 (reader algebra unchanged, numerics bit-identical).
__global__ __launch_bounds__(256, 4) void vq_gemm(const short* __restrict__ ahg,
                                                  const short* __restrict__ alg,
                                                  const short* __restrict__ ehg,
                                                  const short* __restrict__ elg,
                                                  const float* __restrict__ esq,
                                                  float2* __restrict__ pmin2,
                                                  int* __restrict__ pidx) {
    __shared__ __align__(16) short Ah[128 * 32];  // 8 KB each, 32 KB total
    __shared__ __align__(16) short Al[128 * 32];
    __shared__ __align__(16) short Bh[128 * 32];
    __shared__ __align__(16) short Bl[128 * 32];

    const int t = threadIdx.x;
    const int mi = blockIdx.x >> 5, ni = blockIdx.x & 31;
    const size_t row0 = (size_t)mi * 128;
    const int col0 = ni * 128;
    const int lane = t & 63, wave = t >> 6;
    const int wm = wave >> 1, wn = wave & 1;
    const int n15 = lane & 15, quad = lane >> 4;
    const int swz = (n15 >> 1) & 3;

    // staging coords (granule = 8 elems = 16B): granules g=t and g=t+256
    // r = g>>2, c8 = g&3; source octet k = c8 ^ ((r>>1)&3); dest linear g*16B
    const int ar0 = t >> 2, ac0 = t & 3;
    const int ap0 = ac0 ^ ((ar0 >> 1) & 3);
    const int ar1 = (t + 256) >> 2;
    const int ap1 = ac0 ^ ((ar1 >> 1) & 3);   // == ap0 (r+64 -> same s)
    const short* asrc0h = ahg + (size_t)(row0 + ar0) * DDIM + ap0 * 8;
    const short* asrc0l = alg + (size_t)(row0 + ar0) * DDIM + ap0 * 8;
    const short* asrc1h = ahg + (size_t)(row0 + ar1) * DDIM + ap1 * 8;
    const short* asrc1l = alg + (size_t)(row0 + ar1) * DDIM + ap1 * 8;
    const short* bsrc0h = ehg + (size_t)(col0 + ar0) * DDIM + ap0 * 8;
    const short* bsrc0l = elg + (size_t)(col0 + ar0) * DDIM + ap0 * 8;
    const short* bsrc1h = ehg + (size_t)(col0 + ar1) * DDIM + ap1 * 8;
    const short* bsrc1l = elg + (size_t)(col0 + ar1) * DDIM + ap1 * 8;

    f32x4 acc[4][4];
#pragma unroll
    for (int i = 0; i < 4; ++i)
#pragma unroll
        for (int j = 0; j < 4; ++j) {
            acc[i][j][0] = 0.f; acc[i][j][1] = 0.f;
            acc[i][j][2] = 0.f; acc[i][j][3] = 0.f;
        }

#pragma unroll
    for (int ch = 0; ch < 8; ++ch) {
        __syncthreads();  // prior chunk's LDS reads complete
        gload_lds16(asrc0h + ch * 32, &Ah[t * 8]);
        gload_lds16(asrc0l + ch * 32, &Al[t * 8]);
        gload_lds16(asrc1h + ch * 32, &Ah[(t + 256) * 8]);
        gload_lds16(asrc1l + ch * 32, &Al[(t + 256) * 8]);
        gload_lds16(bsrc0h + ch * 32, &Bh[t * 8]);
        gload_lds16(bsrc0l + ch * 32, &Bl[t * 8]);
        gload_lds16(bsrc1h + ch * 32, &Bh[(t + 256) * 8]);
        gload_lds16(bsrc1l + ch * 32, &Bl[(t + 256) * 8]);
        __syncthreads();  // drains vmcnt -> tiles visible

        bf16x8 ah[4], al[4];
#pragma unroll
        for (int i = 0; i < 4; ++i) {
            int off = (wm * 64 + i * 16 + n15) * 32 + ((quad ^ swz) * 8);
            ah[i] = *(const bf16x8*)&Ah[off];
            al[i] = *(const bf16x8*)&Al[off];
        }
#pragma unroll
        for (int j = 0; j < 4; ++j) {
            int boff = (wn * 64 + j * 16 + n15) * 32 + ((quad ^ swz) * 8);
            bf16x8 bh = *(const bf16x8*)&Bh[boff];
            bf16x8 bl = *(const bf16x8*)&Bl[boff];
#pragma unroll
            for (int i = 0; i < 4; ++i) {
                acc[i][j] = __builtin_amdgcn_mfma_f32_16x16x32_bf16(ah[i], bh, acc[i][j], 0, 0, 0);
                acc[i][j] = __builtin_amdgcn_mfma_f32_16x16x32_bf16(ah[i], bl, acc[i][j], 0, 0, 0);
                acc[i][j] = __builtin_amdgcn_mfma_f32_16x16x32_bf16(al[i], bh, acc[i][j], 0, 0, 0);
            }
        }
    }

    // ---- epilogue: per-wave top-2 over its 64 codes (R4 verbatim) ----
    float esqv[4];
#pragma unroll
    for (int j = 0; j < 4; ++j) esqv[j] = esq[col0 + wn * 64 + j * 16 + n15];

#pragma unroll
    for (int i = 0; i < 4; ++i) {
#pragma unroll
        for (int reg = 0; reg < 4; ++reg) {
            float m1 = FLT_MAX, m2 = FLT_MAX;
            int bi = 0;
#pragma unroll
            for (int j = 0; j < 4; ++j) {
                float d = esqv[j] - 2.0f * acc[i][j][reg];
                int code = col0 + wn * 64 + j * 16 + n15;
                if (d < m1) { m2 = m1; m1 = d; bi = code; }
                else if (d < m2) { m2 = d; }
            }
#pragma unroll
            for (int off = 1; off < 16; off <<= 1) {
                float om1 = __shfl_xor(m1, off);
                float om2 = __shfl_xor(m2, off);
                int obi = __shfl_xor(bi, off);
                bool take = (om1 < m1) || (om1 == m1 && obi < bi);
                if (take) { m2 = fminf(m1, om2); m1 = om1; bi = obi; }
                else      { m2 = fminf(om1, m2); }
            }
            if (n15 == 0) {
                int rg = (int)row0 + wm * 64 + i * 16 + quad * 4 + reg;
                int slot = ni * 2 + wn;
                pmin2[(size_t)slot * NROWS + rg] = make_float2(m1, m2);
                pidx[(size_t)slot * NROWS + rg] = bi;
            }
        }
    }
}

// ---- fallback GEMM (R6 verbatim): in-kernel A conversion, small ws ----
__global__ __launch_bounds__(256, 2) void vq_gemm_fb(const float* __restrict__ inp,
                                                     const short* __restrict__ ehg,
                                                     const short* __restrict__ elg,
                                                     const float* __restrict__ esq,
                                                     float2* __restrict__ pmin2,
                                                     int* __restrict__ pidx) {
    __shared__ __align__(16) short Ah[128 * 32];
    __shared__ __align__(16) short Al[128 * 32];
    __shared__ __align__(16) short Bh[128 * 32];
    __shared__ __align__(16) short Bl[128 * 32];

    const int t = threadIdx.x;
    const int mi = blockIdx.x >> 5, ni = blockIdx.x & 31;
    const size_t row0 = (size_t)mi * 128;
    const int col0 = ni * 128;
    const int lane = t & 63, wave = t >> 6;
    const int wm = wave >> 1, wn = wave & 1;
    const int n15 = lane & 15, quad = lane >> 4;
    const int swz = (n15 >> 1) & 3;

    const int ar0 = t >> 2, ac0 = t & 3;
    const int ap0 = ac0 ^ ((ar0 >> 1) & 3);
    const int ar1 = (t + 256) >> 2, ac1 = ac0;
    const int ap1 = ac1 ^ ((ar1 >> 1) & 3);
    const float* asrc0 = inp + (row0 + ar0) * DDIM + ac0 * 8;
    const float* asrc1 = inp + (row0 + ar1) * DDIM + ac1 * 8;
    short* adst0h = &Ah[ar0 * 32 + ap0 * 8];
    short* adst0l = &Al[ar0 * 32 + ap0 * 8];
    short* adst1h = &Ah[ar1 * 32 + ap1 * 8];
    short* adst1l = &Al[ar1 * 32 + ap1 * 8];
    const int br0 = ar0, bp0 = ac0, bk0 = bp0 ^ ((br0 >> 1) & 3);
    const int br1 = ar1, bp1 = ac1, bk1 = bp1 ^ ((br1 >> 1) & 3);
    const short* bsrc0h = ehg + (size_t)(col0 + br0) * DDIM + bk0 * 8;
    const short* bsrc0l = elg + (size_t)(col0 + br0) * DDIM + bk0 * 8;
    const short* bsrc1h = ehg + (size_t)(col0 + br1) * DDIM + bk1 * 8;
    const short* bsrc1l = elg + (size_t)(col0 + br1) * DDIM + bk1 * 8;

    f32x4 acc[4][4];
#pragma unroll
    for (int i = 0; i < 4; ++i)
#pragma unroll
        for (int j = 0; j < 4; ++j) {
            acc[i][j][0] = 0.f; acc[i][j][1] = 0.f;
            acc[i][j][2] = 0.f; acc[i][j][3] = 0.f;
        }

#pragma unroll
    for (int ch = 0; ch < 8; ++ch) {
        __syncthreads();
        gload_lds16(bsrc0h + ch * 32, &Bh[t * 8]);
        gload_lds16(bsrc0l + ch * 32, &Bl[t * 8]);
        gload_lds16(bsrc1h + ch * 32, &Bh[(t + 256) * 8]);
        gload_lds16(bsrc1l + ch * 32, &Bl[(t + 256) * 8]);
        stage8(asrc0 + ch * 32, adst0h, adst0l);
        stage8(asrc1 + ch * 32, adst1h, adst1l);
        __syncthreads();

        bf16x8 ah[4], al[4];
#pragma unroll
        for (int i = 0; i < 4; ++i) {
            int off = (wm * 64 + i * 16 + n15) * 32 + ((quad ^ swz) * 8);
            ah[i] = *(const bf16x8*)&Ah[off];
            al[i] = *(const bf16x8*)&Al[off];
        }
#pragma unroll
        for (int j = 0; j < 4; ++j) {
            int boff = (wn * 64 + j * 16 + n15) * 32 + ((quad ^ swz) * 8);
            bf16x8 bh = *(const bf16x8*)&Bh[boff];
            bf16x8 bl = *(const bf16x8*)&Bl[boff];
#pragma unroll
            for (int i = 0; i < 4; ++i) {
                acc[i][j] = __builtin_amdgcn_mfma_f32_16x16x32_bf16(ah[i], bh, acc[i][j], 0, 0, 0);
                acc[i][j] = __builtin_amdgcn_mfma_f32_16x16x32_bf16(ah[i], bl, acc[i][j], 0, 0, 0);
                acc[i][j] = __builtin_amdgcn_mfma_f32_16x16x32_bf16(al[i], bh, acc[i][j], 0, 0, 0);
            }
        }
    }

    float esqv[4];
#pragma unroll
    for (int j = 0; j < 4; ++j) esqv[j] = esq[col0 + wn * 64 + j * 16 + n15];

#pragma unroll
    for (int i = 0; i < 4; ++i) {
#pragma unroll
        for (int reg = 0; reg < 4; ++reg) {
            float m1 = FLT_MAX, m2 = FLT_MAX;
            int bi = 0;
#pragma unroll
            for (int j = 0; j < 4; ++j) {
                float d = esqv[j] - 2.0f * acc[i][j][reg];
                int code = col0 + wn * 64 + j * 16 + n15;
                if (d < m1) { m2 = m1; m1 = d; bi = code; }
                else if (d < m2) { m2 = d; }
            }
#pragma unroll
            for (int off = 1; off < 16; off <<= 1) {
                float om1 = __shfl_xor(m1, off);
                float om2 = __shfl_xor(m2, off);
                int obi = __shfl_xor(bi, off);
                bool take = (om1 < m1) || (om1 == m1 && obi < bi);
                if (take) { m2 = fminf(m1, om2); m1 = om1; bi = obi; }
                else      { m2 = fminf(om1, m2); }
            }
            if (n15 == 0) {
                int rg = (int)row0 + wm * 64 + i * 16 + quad * 4 + reg;
                int slot = ni * 2 + wn;
                pmin2[(size_t)slot * NROWS + rg] = make_float2(m1, m2);
                pidx[(size_t)slot * NROWS + rg] = bi;
            }
        }
    }
}

// ---- reduce 64 per-wave partials per row; flag near-ties ----
__global__ __launch_bounds__(256) void vq_reduce(const float2* __restrict__ pmin2,
                                                 const int* __restrict__ pidx,
                                                 int* __restrict__ idx_final,
                                                 int* __restrict__ flags,
                                                 int* __restrict__ fcount) {
    int row = blockIdx.x * 256 + threadIdx.x;
    float m1 = FLT_MAX, m2 = FLT_MAX;
    int bi = 0;
    for (int nb = 0; nb < NSLOT; ++nb) {
        float2 p = pmin2[(size_t)nb * NROWS + row];
        int pi = pidx[(size_t)nb * NROWS + row];
        if (p.x < m1) { m2 = fminf(m1, p.y); m1 = p.x; bi = pi; }
        else          { m2 = fminf(m2, p.x); }
    }
    idx_final[row] = bi;
    if (m2 - m1 < GAP_THRESH) {
        int s = atomicAdd(fcount, 1);
        flags[s] = row;
    }
}

// ---- fp32 recheck of flagged rows (exact R1 semantics) ----
__global__ __launch_bounds__(256) void vq_recheck(const float* __restrict__ inp,
                                                  const float* __restrict__ emb,
                                                  const float* __restrict__ esq,
                                                  const int* __restrict__ flags,
                                                  const int* __restrict__ fcount,
                                                  int* __restrict__ idx_final) {
    __shared__ float4 xs[64];
    __shared__ float sv[4];
    __shared__ int si[4];
    const int t = threadIdx.x;
    const int cnt = *fcount;
    for (int f = blockIdx.x; f < cnt; f += gridDim.x) {
        int row = flags[f];
        __syncthreads();
        if (t < 64) xs[t] = ((const float4*)inp)[(size_t)row * 64 + t];
        __syncthreads();
        float m1 = FLT_MAX;
        int bi = 0x7FFFFFFF;
        for (int cc = 0; cc < 16; ++cc) {
            int c = cc * 256 + t;
            const float4* e4 = (const float4*)emb + (size_t)c * 64;
            float dot = 0.f;
            for (int d4 = 0; d4 < 64; ++d4) {
                float4 e = e4[d4];
                float4 x = xs[d4];
                dot += e.x * x.x; dot += e.y * x.y;
                dot += e.z * x.z; dot += e.w * x.w;
            }
            float d = esq[c] - 2.0f * dot;
            if (d < m1 || (d == m1 && c < bi)) { m1 = d; bi = c; }
        }
#pragma unroll
        for (int off = 1; off < 64; off <<= 1) {
            float om = __shfl_xor(m1, off);
            int ob = __shfl_xor(bi, off);
            if (om < m1 || (om == m1 && ob < bi)) { m1 = om; bi = ob; }
        }
        if ((t & 63) == 0) { sv[t >> 6] = m1; si[t >> 6] = bi; }
        __syncthreads();
        if (t == 0) {
            for (int w = 1; w < 4; ++w)
                if (sv[w] < m1 || (sv[w] == m1 && si[w] < bi)) { m1 = sv[w]; bi = si[w]; }
            idx_final[row] = bi;
        }
    }
}

// ---- gather quantized, write indices, per-block loss partial ----
__global__ __launch_bounds__(256) void vq_gather(const float* __restrict__ inp,
                                                 const float* __restrict__ emb,
                                                 const int* __restrict__ idx_final,
                                                 float* __restrict__ out,
                                                 float* __restrict__ loss_part) {
    __shared__ float wsum[4];
    size_t gid = (size_t)blockIdx.x * 256 + threadIdx.x;
    int row = (int)(gid >> 6), c4 = (int)(gid & 63);
    int k = idx_final[row];
    float4 e = ((const float4*)emb)[(size_t)k * 64 + c4];
    float4 x = ((const float4*)inp)[gid];
    ((float4*)out)[gid] = e;
    float dx = e.x - x.x, dy = e.y - x.y, dz = e.z - x.z, dw = e.w - x.w;
    float ls = dx * dx + dy * dy + dz * dz + dw * dw;
#pragma unroll
    for (int off = 32; off >= 1; off >>= 1) ls += __shfl_down(ls, off);
    if ((threadIdx.x & 63) == 0) wsum[threadIdx.x >> 6] = ls;
    if (c4 == 0) out[(size_t)QSIZE + 1 + row] = (float)k;
    __syncthreads();
    if (threadIdx.x == 0)
        loss_part[blockIdx.x] = wsum[0] + wsum[1] + wsum[2] + wsum[3];
}

__global__ __launch_bounds__(256) void loss_kernel(const float* __restrict__ loss_part,
                                                   float* __restrict__ out) {
    __shared__ float sw[4];
    int t = threadIdx.x;
    float s = 0.0f;
    for (int i = t; i < NLBLK; i += 256) s += loss_part[i];
#pragma unroll
    for (int off = 32; off >= 1; off >>= 1) s += __shfl_down(s, off);
    if ((t & 63) == 0) sw[t >> 6] = s;
    __syncthreads();
    if (t == 0)
        out[QSIZE] = (sw[0] + sw[1] + sw[2] + sw[3]) * (1.0f / 16777216.0f);
}

extern "C" void kernel_launch(void* const* d_in, const int* in_sizes, int n_in,
                              void* d_out, int out_size, void* d_ws, size_t ws_size,
                              hipStream_t stream) {
    const float* inp = (const float*)d_in[0];
    const float* emb = (const float*)d_in[1];
    float* out = (float*)d_out;
    float* ws = (float*)d_ws;

    float* esq = ws;
    int* fcount = (int*)ws + O_FCOUNT;
    int* flags = (int*)ws + O_FLAGS;
    int* idx_final = (int*)ws + O_IDXF;
    float* loss_part = ws + O_LPART;
    short* eh = (short*)(ws + O_EMBH);
    short* el = (short*)(ws + O_EMBL);

    // partials in d_out's quantized region (overwritten by vq_gather)
    float2* pmin2 = (float2*)out;                 // [0, 8388608) floats
    int* pidx = (int*)out + 8388608;              // [8388608, 12582912)

    hipLaunchKernelGGL(esq_conv, dim3(KCODES), dim3(64), 0, stream, emb, ws, eh, el);

    if (ws_size >= WS_NEED_FLOATS * 4ull) {
        short* ah = (short*)(ws + O_AH);
        short* al = (short*)(ws + O_AL);
        hipLaunchKernelGGL(inp_conv, dim3(8192), dim3(256), 0, stream, inp, ah, al);
        hipLaunchKernelGGL(vq_gemm, dim3((NROWS / 128) * 32), dim3(256), 0, stream,
                           ah, al, eh, el, esq, pmin2, pidx);
    } else {
        hipLaunchKernelGGL(vq_gemm_fb, dim3((NROWS / 128) * 32), dim3(256), 0, stream,
                           inp, eh, el, esq, pmin2, pidx);
    }

    hipLaunchKernelGGL(vq_reduce, dim3(NROWS / 256), dim3(256), 0, stream,
                       pmin2, pidx, idx_final, flags, fcount);
    hipLaunchKernelGGL(vq_recheck, dim3(256), dim3(256), 0, stream,
                       inp, emb, esq, flags, fcount, idx_final);
    hipLaunchKernelGGL(vq_gather, dim3(NLBLK), dim3(256), 0, stream,
                       inp, emb, idx_final, out, loss_part);
    hipLaunchKernelGGL(loss_kernel, dim3(1), dim3(256), 0, stream, loss_part, out);
}

// Round 7
// 771.710 us; speedup vs baseline: 30.2692x; 1.0062x over previous
//
#include <hip/hip_runtime.h>
#include <float.h>
#include <stdint.h>

// VectorQuantizer R13: R12 (proven 512us GEMM, 776us total) + occupancy push.
//  - vq_gemm re-partitioned: 512 threads, 8 waves as 4M x 2N (wave tile
//    32x64, acc[2][4] = 32 AGPR, half of R12). __launch_bounds__(512, 6)
//    -> 80-reg cap -> 3 blocks/CU x 8 waves = 24 waves/CU (75% occupancy
//    target vs R12's 44%). Same 128x128 tile, same 32KB LDS, same octet
//    swizzle, same per-output accumulation order (ch asc; hh,hl,lh with
//    identical fragments) -> numerics bit-identical to R12.
//    Staging: 1 granule (16B) per thread per matrix = 4 gload_lds/thread.
//  - vq_recheck grid 256 -> 1024 blocks (kernel already grid-stride safe).
//  - Everything else R12 verbatim.
// d_out = [quantized 16777216 f32][loss 1][indices 65536] ; scratch reuse:
//   pmin2 = 64 slots x float2 x 65536 rows (33.5MB), pidx 16.8MB
// d_ws floats: esq[0,4096) | fcount@4097 | flags@4100 | idx_final@69636 |
//   loss_part@135172 | emb_hi@151556 | emb_lo@675844 | a_hi@1200384 |
//   a_lo@9588992 (end 17977600 floats = 71.9MB; fallback needs only 4.8MB)

#define DDIM 256
#define KCODES 4096
#define NROWS 65536
#define QSIZE 16777216
#define NSLOT 64
#define NLBLK 16384
#define GAP_THRESH 0.02f

#define O_FCOUNT 4097
#define O_FLAGS 4100
#define O_IDXF 69636
#define O_LPART 135172
#define O_EMBH 151556
#define O_EMBL 675844
#define O_AH 1200384
#define O_AL 9588992
#define WS_NEED_FLOATS 17977600ull

typedef short bf16x8 __attribute__((ext_vector_type(8)));
typedef float f32x4 __attribute__((ext_vector_type(4)));

__device__ __forceinline__ void gload_lds16(const void* g, void* l) {
    __builtin_amdgcn_global_load_lds(
        (const __attribute__((address_space(1))) void*)g,
        (__attribute__((address_space(3))) void*)l, 16, 0, 0);
}

// ---- esq + emb hi/lo conversion + init (one pass over emb) ----
__global__ __launch_bounds__(64) void esq_conv(const float* __restrict__ emb,
                                               float* __restrict__ ws,
                                               short* __restrict__ eh,
                                               short* __restrict__ el) {
    int c = blockIdx.x, l = threadIdx.x;
    const float4* e4 = (const float4*)(emb + (size_t)c * DDIM);
    float4 v = e4[l];
    float s = v.x * v.x + v.y * v.y + v.z * v.z + v.w * v.w;
    float f[4] = {v.x, v.y, v.z, v.w};
    uint32_t hu[4], lu[4];
#pragma unroll
    for (int k = 0; k < 4; ++k) {
        uint32_t u = __float_as_uint(f[k]);
        uint32_t h = u & 0xFFFF0000u;
        hu[k] = h;
        lu[k] = __float_as_uint(f[k] - __uint_as_float(h));
    }
    uint2 hv, lv;
    hv.x = __builtin_amdgcn_perm(hu[1], hu[0], 0x07060302u);
    hv.y = __builtin_amdgcn_perm(hu[3], hu[2], 0x07060302u);
    lv.x = __builtin_amdgcn_perm(lu[1], lu[0], 0x07060302u);
    lv.y = __builtin_amdgcn_perm(lu[3], lu[2], 0x07060302u);
    *(uint2*)&eh[(size_t)c * DDIM + l * 4] = hv;
    *(uint2*)&el[(size_t)c * DDIM + l * 4] = lv;
#pragma unroll
    for (int off = 32; off >= 1; off >>= 1) s += __shfl_down(s, off);
    if (l == 0) ws[c] = s;
    if (c == 0 && l == 0) ((int*)ws)[O_FCOUNT] = 0;
}

// split fp32 -> (hi bf16, lo bf16), pack 8 elems, write 16B hi + 16B lo
__device__ __forceinline__ void conv8(float4 a, float4 b,
                                      short* __restrict__ dh,
                                      short* __restrict__ dl) {
    float f[8] = {a.x, a.y, a.z, a.w, b.x, b.y, b.z, b.w};
    uint32_t hu[8], lu[8];
#pragma unroll
    for (int k = 0; k < 8; ++k) {
        uint32_t u = __float_as_uint(f[k]);
        uint32_t h = u & 0xFFFF0000u;
        hu[k] = h;
        lu[k] = __float_as_uint(f[k] - __uint_as_float(h));
    }
    uint4 hv, lv;
    hv.x = __builtin_amdgcn_perm(hu[1], hu[0], 0x07060302u);
    hv.y = __builtin_amdgcn_perm(hu[3], hu[2], 0x07060302u);
    hv.z = __builtin_amdgcn_perm(hu[5], hu[4], 0x07060302u);
    hv.w = __builtin_amdgcn_perm(hu[7], hu[6], 0x07060302u);
    lv.x = __builtin_amdgcn_perm(lu[1], lu[0], 0x07060302u);
    lv.y = __builtin_amdgcn_perm(lu[3], lu[2], 0x07060302u);
    lv.z = __builtin_amdgcn_perm(lu[5], lu[4], 0x07060302u);
    lv.w = __builtin_amdgcn_perm(lu[7], lu[6], 0x07060302u);
    *(uint4*)dh = hv;
    *(uint4*)dl = lv;
}

__device__ __forceinline__ void stage8(const float* __restrict__ p,
                                       short* __restrict__ dh,
                                       short* __restrict__ dl) {
    float4 a = *(const float4*)p;
    float4 b = *(const float4*)(p + 4);
    conv8(a, b, dh, dl);
}

// ---- A pre-conversion: inp fp32 -> bf16 hi/lo (memory-bound, ~25us) ----
__global__ __launch_bounds__(256) void inp_conv(const float* __restrict__ inp,
                                                short* __restrict__ ahg,
                                                short* __restrict__ alg) {
    size_t g = (size_t)blockIdx.x * 256 + threadIdx.x;  // granule of 8 elems
    const float* p = inp + g * 8;
    float4 a = *(const float4*)p;
    float4 b = *(const float4*)(p + 4);
    conv8(a, b, ahg + g * 8, alg + g * 8);
}

// ---- main GEMM: 128x128 tile, 512 thr (8 waves 4Mx2N), 8 chunks ----
// All four tiles via gload_lds: dest linear (slot c0 of row r0), source
// octet p0 = c0 ^ ((r0>>1)&3) -> physical slot p holds logical octet p^s.
// Reader: row = 16k + n15 -> (row>>1)&3 == swz -> logical octet = quad. ✓
__global__ __launch_bounds__(512, 6) void vq_gemm(const short* __restrict__ ahg,
                                                  const short* __restrict__ alg,
                                                  const short* __restrict__ ehg,
                                                  const short* __restrict__ elg,
                                                  const float* __restrict__ esq,
                                                  float2* __restrict__ pmin2,
                                                  int* __restrict__ pidx) {
    __shared__ __align__(16) short Ah[128 * 32];  // 8 KB each, 32 KB total
    __shared__ __align__(16) short Al[128 * 32];
    __shared__ __align__(16) short Bh[128 * 32];
    __shared__ __align__(16) short Bl[128 * 32];

    const int t = threadIdx.x;                    // 0..511
    const int mi = blockIdx.x >> 5, ni = blockIdx.x & 31;
    const size_t row0 = (size_t)mi * 128;
    const int col0 = ni * 128;
    const int lane = t & 63, wave = t >> 6;       // wave 0..7
    const int wm = wave >> 1, wn = wave & 1;      // 4 M-waves x 2 N-waves
    const int n15 = lane & 15, quad = lane >> 4;
    const int swz = (n15 >> 1) & 3;

    // staging: 1 granule (8 elems = 16B) per thread per matrix
    // r0 = t>>2 covers 0..127; c0 = t&3; source octet p0 = c0^((r0>>1)&3)
    const int r0 = t >> 2, c0 = t & 3;
    const int p0 = c0 ^ ((r0 >> 1) & 3);
    const short* asrch = ahg + (size_t)(row0 + r0) * DDIM + p0 * 8;
    const short* asrcl = alg + (size_t)(row0 + r0) * DDIM + p0 * 8;
    const short* bsrch = ehg + (size_t)(col0 + r0) * DDIM + p0 * 8;
    const short* bsrcl = elg + (size_t)(col0 + r0) * DDIM + p0 * 8;
    const int d0 = t * 8;                         // linear LDS dest

    f32x4 acc[2][4];
#pragma unroll
    for (int i = 0; i < 2; ++i)
#pragma unroll
        for (int j = 0; j < 4; ++j) {
            acc[i][j][0] = 0.f; acc[i][j][1] = 0.f;
            acc[i][j][2] = 0.f; acc[i][j][3] = 0.f;
        }

#pragma unroll
    for (int ch = 0; ch < 8; ++ch) {
        __syncthreads();  // prior chunk's LDS reads complete
        gload_lds16(asrch + ch * 32, &Ah[d0]);
        gload_lds16(asrcl + ch * 32, &Al[d0]);
        gload_lds16(bsrch + ch * 32, &Bh[d0]);
        gload_lds16(bsrcl + ch * 32, &Bl[d0]);
        __syncthreads();  // drains vmcnt -> tiles visible

        bf16x8 ah[2], al[2];
#pragma unroll
        for (int i = 0; i < 2; ++i) {
            int off = (wm * 32 + i * 16 + n15) * 32 + ((quad ^ swz) * 8);
            ah[i] = *(const bf16x8*)&Ah[off];
            al[i] = *(const bf16x8*)&Al[off];
        }
#pragma unroll
        for (int j = 0; j < 4; ++j) {
            int boff = (wn * 64 + j * 16 + n15) * 32 + ((quad ^ swz) * 8);
            bf16x8 bh = *(const bf16x8*)&Bh[boff];
            bf16x8 bl = *(const bf16x8*)&Bl[boff];
#pragma unroll
            for (int i = 0; i < 2; ++i) {
                acc[i][j] = __builtin_amdgcn_mfma_f32_16x16x32_bf16(ah[i], bh, acc[i][j], 0, 0, 0);
                acc[i][j] = __builtin_amdgcn_mfma_f32_16x16x32_bf16(ah[i], bl, acc[i][j], 0, 0, 0);
                acc[i][j] = __builtin_amdgcn_mfma_f32_16x16x32_bf16(al[i], bh, acc[i][j], 0, 0, 0);
            }
        }
    }

    // ---- epilogue: per-wave top-2 over its 64 codes (R4 semantics) ----
    float esqv[4];
#pragma unroll
    for (int j = 0; j < 4; ++j) esqv[j] = esq[col0 + wn * 64 + j * 16 + n15];

#pragma unroll
    for (int i = 0; i < 2; ++i) {
#pragma unroll
        for (int reg = 0; reg < 4; ++reg) {
            float m1 = FLT_MAX, m2 = FLT_MAX;
            int bi = 0;
#pragma unroll
            for (int j = 0; j < 4; ++j) {
                float d = esqv[j] - 2.0f * acc[i][j][reg];
                int code = col0 + wn * 64 + j * 16 + n15;
                if (d < m1) { m2 = m1; m1 = d; bi = code; }
                else if (d < m2) { m2 = d; }
            }
#pragma unroll
            for (int off = 1; off < 16; off <<= 1) {
                float om1 = __shfl_xor(m1, off);
                float om2 = __shfl_xor(m2, off);
                int obi = __shfl_xor(bi, off);
                bool take = (om1 < m1) || (om1 == m1 && obi < bi);
                if (take) { m2 = fminf(m1, om2); m1 = om1; bi = obi; }
                else      { m2 = fminf(om1, m2); }
            }
            if (n15 == 0) {
                int rg = (int)row0 + wm * 32 + i * 16 + quad * 4 + reg;
                int slot = ni * 2 + wn;
                pmin2[(size_t)slot * NROWS + rg] = make_float2(m1, m2);
                pidx[(size_t)slot * NROWS + rg] = bi;
            }
        }
    }
}

// ---- fallback GEMM (R6 verbatim): in-kernel A conversion, small ws ----
__global__ __launch_bounds__(256, 2) void vq_gemm_fb(const float* __restrict__ inp,
                                                     const short* __restrict__ ehg,
                                                     const short* __restrict__ elg,
                                                     const float* __restrict__ esq,
                                                     float2* __restrict__ pmin2,
                                                     int* __restrict__ pidx) {
    __shared__ __align__(16) short Ah[128 * 32];
    __shared__ __align__(16) short Al[128 * 32];
    __shared__ __align__(16) short Bh[128 * 32];
    __shared__ __align__(16) short Bl[128 * 32];

    const int t = threadIdx.x;
    const int mi = blockIdx.x >> 5, ni = blockIdx.x & 31;
    const size_t row0 = (size_t)mi * 128;
    const int col0 = ni * 128;
    const int lane = t & 63, wave = t >> 6;
    const int wm = wave >> 1, wn = wave & 1;
    const int n15 = lane & 15, quad = lane >> 4;
    const int swz = (n15 >> 1) & 3;

    const int ar0 = t >> 2, ac0 = t & 3;
    const int ap0 = ac0 ^ ((ar0 >> 1) & 3);
    const int ar1 = (t + 256) >> 2, ac1 = ac0;
    const int ap1 = ac1 ^ ((ar1 >> 1) & 3);
    const float* asrc0 = inp + (row0 + ar0) * DDIM + ac0 * 8;
    const float* asrc1 = inp + (row0 + ar1) * DDIM + ac1 * 8;
    short* adst0h = &Ah[ar0 * 32 + ap0 * 8];
    short* adst0l = &Al[ar0 * 32 + ap0 * 8];
    short* adst1h = &Ah[ar1 * 32 + ap1 * 8];
    short* adst1l = &Al[ar1 * 32 + ap1 * 8];
    const int br0 = ar0, bp0 = ac0, bk0 = bp0 ^ ((br0 >> 1) & 3);
    const int br1 = ar1, bp1 = ac1, bk1 = bp1 ^ ((br1 >> 1) & 3);
    const short* bsrc0h = ehg + (size_t)(col0 + br0) * DDIM + bk0 * 8;
    const short* bsrc0l = elg + (size_t)(col0 + br0) * DDIM + bk0 * 8;
    const short* bsrc1h = ehg + (size_t)(col0 + br1) * DDIM + bk1 * 8;
    const short* bsrc1l = elg + (size_t)(col0 + br1) * DDIM + bk1 * 8;

    f32x4 acc[4][4];
#pragma unroll
    for (int i = 0; i < 4; ++i)
#pragma unroll
        for (int j = 0; j < 4; ++j) {
            acc[i][j][0] = 0.f; acc[i][j][1] = 0.f;
            acc[i][j][2] = 0.f; acc[i][j][3] = 0.f;
        }

#pragma unroll
    for (int ch = 0; ch < 8; ++ch) {
        __syncthreads();
        gload_lds16(bsrc0h + ch * 32, &Bh[t * 8]);
        gload_lds16(bsrc0l + ch * 32, &Bl[t * 8]);
        gload_lds16(bsrc1h + ch * 32, &Bh[(t + 256) * 8]);
        gload_lds16(bsrc1l + ch * 32, &Bl[(t + 256) * 8]);
        stage8(asrc0 + ch * 32, adst0h, adst0l);
        stage8(asrc1 + ch * 32, adst1h, adst1l);
        __syncthreads();

        bf16x8 ah[4], al[4];
#pragma unroll
        for (int i = 0; i < 4; ++i) {
            int off = (wm * 64 + i * 16 + n15) * 32 + ((quad ^ swz) * 8);
            ah[i] = *(const bf16x8*)&Ah[off];
            al[i] = *(const bf16x8*)&Al[off];
        }
#pragma unroll
        for (int j = 0; j < 4; ++j) {
            int boff = (wn * 64 + j * 16 + n15) * 32 + ((quad ^ swz) * 8);
            bf16x8 bh = *(const bf16x8*)&Bh[boff];
            bf16x8 bl = *(const bf16x8*)&Bl[boff];
#pragma unroll
            for (int i = 0; i < 4; ++i) {
                acc[i][j] = __builtin_amdgcn_mfma_f32_16x16x32_bf16(ah[i], bh, acc[i][j], 0, 0, 0);
                acc[i][j] = __builtin_amdgcn_mfma_f32_16x16x32_bf16(ah[i], bl, acc[i][j], 0, 0, 0);
                acc[i][j] = __builtin_amdgcn_mfma_f32_16x16x32_bf16(al[i], bh, acc[i][j], 0, 0, 0);
            }
        }
    }

    float esqv[4];
#pragma unroll
    for (int j = 0; j < 4; ++j) esqv[j] = esq[col0 + wn * 64 + j * 16 + n15];

#pragma unroll
    for (int i = 0; i < 4; ++i) {
#pragma unroll
        for (int reg = 0; reg < 4; ++reg) {
            float m1 = FLT_MAX, m2 = FLT_MAX;
            int bi = 0;
#pragma unroll
            for (int j = 0; j < 4; ++j) {
                float d = esqv[j] - 2.0f * acc[i][j][reg];
                int code = col0 + wn * 64 + j * 16 + n15;
                if (d < m1) { m2 = m1; m1 = d; bi = code; }
                else if (d < m2) { m2 = d; }
            }
#pragma unroll
            for (int off = 1; off < 16; off <<= 1) {
                float om1 = __shfl_xor(m1, off);
                float om2 = __shfl_xor(m2, off);
                int obi = __shfl_xor(bi, off);
                bool take = (om1 < m1) || (om1 == m1 && obi < bi);
                if (take) { m2 = fminf(m1, om2); m1 = om1; bi = obi; }
                else      { m2 = fminf(om1, m2); }
            }
            if (n15 == 0) {
                int rg = (int)row0 + wm * 64 + i * 16 + quad * 4 + reg;
                int slot = ni * 2 + wn;
                pmin2[(size_t)slot * NROWS + rg] = make_float2(m1, m2);
                pidx[(size_t)slot * NROWS + rg] = bi;
            }
        }
    }
}

// ---- reduce 64 per-wave partials per row; flag near-ties ----
__global__ __launch_bounds__(256) void vq_reduce(const float2* __restrict__ pmin2,
                                                 const int* __restrict__ pidx,
                                                 int* __restrict__ idx_final,
                                                 int* __restrict__ flags,
                                                 int* __restrict__ fcount) {
    int row = blockIdx.x * 256 + threadIdx.x;
    float m1 = FLT_MAX, m2 = FLT_MAX;
    int bi = 0;
    for (int nb = 0; nb < NSLOT; ++nb) {
        float2 p = pmin2[(size_t)nb * NROWS + row];
        int pi = pidx[(size_t)nb * NROWS + row];
        if (p.x < m1) { m2 = fminf(m1, p.y); m1 = p.x; bi = pi; }
        else          { m2 = fminf(m2, p.x); }
    }
    idx_final[row] = bi;
    if (m2 - m1 < GAP_THRESH) {
        int s = atomicAdd(fcount, 1);
        flags[s] = row;
    }
}

// ---- fp32 recheck of flagged rows (exact R1 semantics) ----
__global__ __launch_bounds__(256) void vq_recheck(const float* __restrict__ inp,
                                                  const float* __restrict__ emb,
                                                  const float* __restrict__ esq,
                                                  const int* __restrict__ flags,
                                                  const int* __restrict__ fcount,
                                                  int* __restrict__ idx_final) {
    __shared__ float4 xs[64];
    __shared__ float sv[4];
    __shared__ int si[4];
    const int t = threadIdx.x;
    const int cnt = *fcount;
    for (int f = blockIdx.x; f < cnt; f += gridDim.x) {
        int row = flags[f];
        __syncthreads();
        if (t < 64) xs[t] = ((const float4*)inp)[(size_t)row * 64 + t];
        __syncthreads();
        float m1 = FLT_MAX;
        int bi = 0x7FFFFFFF;
        for (int cc = 0; cc < 16; ++cc) {
            int c = cc * 256 + t;
            const float4* e4 = (const float4*)emb + (size_t)c * 64;
            float dot = 0.f;
            for (int d4 = 0; d4 < 64; ++d4) {
                float4 e = e4[d4];
                float4 x = xs[d4];
                dot += e.x * x.x; dot += e.y * x.y;
                dot += e.z * x.z; dot += e.w * x.w;
            }
            float d = esq[c] - 2.0f * dot;
            if (d < m1 || (d == m1 && c < bi)) { m1 = d; bi = c; }
        }
#pragma unroll
        for (int off = 1; off < 64; off <<= 1) {
            float om = __shfl_xor(m1, off);
            int ob = __shfl_xor(bi, off);
            if (om < m1 || (om == m1 && ob < bi)) { m1 = om; bi = ob; }
        }
        if ((t & 63) == 0) { sv[t >> 6] = m1; si[t >> 6] = bi; }
        __syncthreads();
        if (t == 0) {
            for (int w = 1; w < 4; ++w)
                if (sv[w] < m1 || (sv[w] == m1 && si[w] < bi)) { m1 = sv[w]; bi = si[w]; }
            idx_final[row] = bi;
        }
    }
}

// ---- gather quantized, write indices, per-block loss partial ----
__global__ __launch_bounds__(256) void vq_gather(const float* __restrict__ inp,
                                                 const float* __restrict__ emb,
                                                 const int* __restrict__ idx_final,
                                                 float* __restrict__ out,
                                                 float* __restrict__ loss_part) {
    __shared__ float wsum[4];
    size_t gid = (size_t)blockIdx.x * 256 + threadIdx.x;
    int row = (int)(gid >> 6), c4 = (int)(gid & 63);
    int k = idx_final[row];
    float4 e = ((const float4*)emb)[(size_t)k * 64 + c4];
    float4 x = ((const float4*)inp)[gid];
    ((float4*)out)[gid] = e;
    float dx = e.x - x.x, dy = e.y - x.y, dz = e.z - x.z, dw = e.w - x.w;
    float ls = dx * dx + dy * dy + dz * dz + dw * dw;
#pragma unroll
    for (int off = 32; off >= 1; off >>= 1) ls += __shfl_down(ls, off);
    if ((threadIdx.x & 63) == 0) wsum[threadIdx.x >> 6] = ls;
    if (c4 == 0) out[(size_t)QSIZE + 1 + row] = (float)k;
    __syncthreads();
    if (threadIdx.x == 0)
        loss_part[blockIdx.x] = wsum[0] + wsum[1] + wsum[2] + wsum[3];
}

__global__ __launch_bounds__(256) void loss_kernel(const float* __restrict__ loss_part,
                                                   float* __restrict__ out) {
    __shared__ float sw[4];
    int t = threadIdx.x;
    float s = 0.0f;
    for (int i = t; i < NLBLK; i += 256) s += loss_part[i];
#pragma unroll
    for (int off = 32; off >= 1; off >>= 1) s += __shfl_down(s, off);
    if ((t & 63) == 0) sw[t >> 6] = s;
    __syncthreads();
    if (t == 0)
        out[QSIZE] = (sw[0] + sw[1] + sw[2] + sw[3]) * (1.0f / 16777216.0f);
}

extern "C" void kernel_launch(void* const* d_in, const int* in_sizes, int n_in,
                              void* d_out, int out_size, void* d_ws, size_t ws_size,
                              hipStream_t stream) {
    const float* inp = (const float*)d_in[0];
    const float* emb = (const float*)d_in[1];
    float* out = (float*)d_out;
    float* ws = (float*)d_ws;

    float* esq = ws;
    int* fcount = (int*)ws + O_FCOUNT;
    int* flags = (int*)ws + O_FLAGS;
    int* idx_final = (int*)ws + O_IDXF;
    float* loss_part = ws + O_LPART;
    short* eh = (short*)(ws + O_EMBH);
    short* el = (short*)(ws + O_EMBL);

    // partials in d_out's quantized region (overwritten by vq_gather)
    float2* pmin2 = (float2*)out;                 // [0, 8388608) floats
    int* pidx = (int*)out + 8388608;              // [8388608, 12582912)

    hipLaunchKernelGGL(esq_conv, dim3(KCODES), dim3(64), 0, stream, emb, ws, eh, el);

    if (ws_size >= WS_NEED_FLOATS * 4ull) {
        short* ah = (short*)(ws + O_AH);
        short* al = (short*)(ws + O_AL);
        hipLaunchKernelGGL(inp_conv, dim3(8192), dim3(256), 0, stream, inp, ah, al);
        hipLaunchKernelGGL(vq_gemm, dim3((NROWS / 128) * 32), dim3(512), 0, stream,
                           ah, al, eh, el, esq, pmin2, pidx);
    } else {
        hipLaunchKernelGGL(vq_gemm_fb, dim3((NROWS / 128) * 32), dim3(256), 0, stream,
                           inp, eh, el, esq, pmin2, pidx);
    }

    hipLaunchKernelGGL(vq_reduce, dim3(NROWS / 256), dim3(256), 0, stream,
                       pmin2, pidx, idx_final, flags, fcount);
    hipLaunchKernelGGL(vq_recheck, dim3(1024), dim3(256), 0, stream,
                       inp, emb, esq, flags, fcount, idx_final);
    hipLaunchKernelGGL(vq_gather, dim3(NLBLK), dim3(256), 0, stream,
                       inp, emb, idx_final, out, loss_part);
    hipLaunchKernelGGL(loss_kernel, dim3(1), dim3(256), 0, stream, loss_part, out);
}

// Round 8
// 736.166 us; speedup vs baseline: 31.7307x; 1.0483x over previous
//
#include <hip/hip_runtime.h>
#include <float.h>
#include <stdint.h>

// VectorQuantizer R14: R13 frozen GEMM (507us, 813 TF ~= 2-barrier ceiling)
// + recheck latency fix. R13 post-mortem: occupancy 44->65% gave only +1%
// GEMM -> GEMM is structure-ceiling-bound; the remaining ~170us of the
// 264us non-GEMM tail is vq_recheck's 88us SERIAL per-row latency (one
// block streams 4MB emb with 1KB-strided latency-bound loads; R10 pathology
// measured 88.7us/row/block).
//  Fix: one flagged row -> 16 blocks (256 codes each). Per thread: one
//  code's fp32 distance with the EXACT old accumulation order (bit-identical
//  d), packed into sortable u64 key (monotone-float<<32 | code); wave+block
//  min-reduce; global atomicMin per flag slot (deterministic, exact old
//  tie rule: min d, tie -> lowest code). vq_unpack writes idx_final.
//  vq_reduce inits keys[s]=~0 when flagging (keys==nullptr in fallback).
// d_out = [quantized 16777216 f32][loss 1][indices 65536] ; scratch reuse:
//   pmin2 = 64 slots x float2 x 65536 rows (33.5MB), pidx 16.8MB
// d_ws floats: esq[0,4096) | fcount@4097 | flags@4100 | idx_final@69636 |
//   loss_part@135172 | emb_hi@151556 | emb_lo@675844 | a_hi@1200384 |
//   a_lo@9588992 | keys@17977600 (u64 x 65536) -> end 18108672 fl = 72.4MB

#define DDIM 256
#define KCODES 4096
#define NROWS 65536
#define QSIZE 16777216
#define NSLOT 64
#define NLBLK 16384
#define GAP_THRESH 0.02f

#define O_FCOUNT 4097
#define O_FLAGS 4100
#define O_IDXF 69636
#define O_LPART 135172
#define O_EMBH 151556
#define O_EMBL 675844
#define O_AH 1200384
#define O_AL 9588992
#define O_KEYS 17977600
#define WS_NEED_FLOATS 18108672ull

typedef short bf16x8 __attribute__((ext_vector_type(8)));
typedef float f32x4 __attribute__((ext_vector_type(4)));

__device__ __forceinline__ void gload_lds16(const void* g, void* l) {
    __builtin_amdgcn_global_load_lds(
        (const __attribute__((address_space(1))) void*)g,
        (__attribute__((address_space(3))) void*)l, 16, 0, 0);
}

// ---- esq + emb hi/lo conversion + init (one pass over emb) ----
__global__ __launch_bounds__(64) void esq_conv(const float* __restrict__ emb,
                                               float* __restrict__ ws,
                                               short* __restrict__ eh,
                                               short* __restrict__ el) {
    int c = blockIdx.x, l = threadIdx.x;
    const float4* e4 = (const float4*)(emb + (size_t)c * DDIM);
    float4 v = e4[l];
    float s = v.x * v.x + v.y * v.y + v.z * v.z + v.w * v.w;
    float f[4] = {v.x, v.y, v.z, v.w};
    uint32_t hu[4], lu[4];
#pragma unroll
    for (int k = 0; k < 4; ++k) {
        uint32_t u = __float_as_uint(f[k]);
        uint32_t h = u & 0xFFFF0000u;
        hu[k] = h;
        lu[k] = __float_as_uint(f[k] - __uint_as_float(h));
    }
    uint2 hv, lv;
    hv.x = __builtin_amdgcn_perm(hu[1], hu[0], 0x07060302u);
    hv.y = __builtin_amdgcn_perm(hu[3], hu[2], 0x07060302u);
    lv.x = __builtin_amdgcn_perm(lu[1], lu[0], 0x07060302u);
    lv.y = __builtin_amdgcn_perm(lu[3], lu[2], 0x07060302u);
    *(uint2*)&eh[(size_t)c * DDIM + l * 4] = hv;
    *(uint2*)&el[(size_t)c * DDIM + l * 4] = lv;
#pragma unroll
    for (int off = 32; off >= 1; off >>= 1) s += __shfl_down(s, off);
    if (l == 0) ws[c] = s;
    if (c == 0 && l == 0) ((int*)ws)[O_FCOUNT] = 0;
}

// split fp32 -> (hi bf16, lo bf16), pack 8 elems, write 16B hi + 16B lo
__device__ __forceinline__ void conv8(float4 a, float4 b,
                                      short* __restrict__ dh,
                                      short* __restrict__ dl) {
    float f[8] = {a.x, a.y, a.z, a.w, b.x, b.y, b.z, b.w};
    uint32_t hu[8], lu[8];
#pragma unroll
    for (int k = 0; k < 8; ++k) {
        uint32_t u = __float_as_uint(f[k]);
        uint32_t h = u & 0xFFFF0000u;
        hu[k] = h;
        lu[k] = __float_as_uint(f[k] - __uint_as_float(h));
    }
    uint4 hv, lv;
    hv.x = __builtin_amdgcn_perm(hu[1], hu[0], 0x07060302u);
    hv.y = __builtin_amdgcn_perm(hu[3], hu[2], 0x07060302u);
    hv.z = __builtin_amdgcn_perm(hu[5], hu[4], 0x07060302u);
    hv.w = __builtin_amdgcn_perm(hu[7], hu[6], 0x07060302u);
    lv.x = __builtin_amdgcn_perm(lu[1], lu[0], 0x07060302u);
    lv.y = __builtin_amdgcn_perm(lu[3], lu[2], 0x07060302u);
    lv.z = __builtin_amdgcn_perm(lu[5], lu[4], 0x07060302u);
    lv.w = __builtin_amdgcn_perm(lu[7], lu[6], 0x07060302u);
    *(uint4*)dh = hv;
    *(uint4*)dl = lv;
}

__device__ __forceinline__ void stage8(const float* __restrict__ p,
                                       short* __restrict__ dh,
                                       short* __restrict__ dl) {
    float4 a = *(const float4*)p;
    float4 b = *(const float4*)(p + 4);
    conv8(a, b, dh, dl);
}

// ---- A pre-conversion: inp fp32 -> bf16 hi/lo (memory-bound, ~25us) ----
__global__ __launch_bounds__(256) void inp_conv(const float* __restrict__ inp,
                                                short* __restrict__ ahg,
                                                short* __restrict__ alg) {
    size_t g = (size_t)blockIdx.x * 256 + threadIdx.x;  // granule of 8 elems
    const float* p = inp + g * 8;
    float4 a = *(const float4*)p;
    float4 b = *(const float4*)(p + 4);
    conv8(a, b, ahg + g * 8, alg + g * 8);
}

// ---- main GEMM: 128x128 tile, 512 thr (8 waves 4Mx2N), 8 chunks ----
// R13 verbatim (proven 507us / 813 TF).
__global__ __launch_bounds__(512, 6) void vq_gemm(const short* __restrict__ ahg,
                                                  const short* __restrict__ alg,
                                                  const short* __restrict__ ehg,
                                                  const short* __restrict__ elg,
                                                  const float* __restrict__ esq,
                                                  float2* __restrict__ pmin2,
                                                  int* __restrict__ pidx) {
    __shared__ __align__(16) short Ah[128 * 32];  // 8 KB each, 32 KB total
    __shared__ __align__(16) short Al[128 * 32];
    __shared__ __align__(16) short Bh[128 * 32];
    __shared__ __align__(16) short Bl[128 * 32];

    const int t = threadIdx.x;                    // 0..511
    const int mi = blockIdx.x >> 5, ni = blockIdx.x & 31;
    const size_t row0 = (size_t)mi * 128;
    const int col0 = ni * 128;
    const int lane = t & 63, wave = t >> 6;       // wave 0..7
    const int wm = wave >> 1, wn = wave & 1;      // 4 M-waves x 2 N-waves
    const int n15 = lane & 15, quad = lane >> 4;
    const int swz = (n15 >> 1) & 3;

    const int r0 = t >> 2, c0 = t & 3;
    const int p0 = c0 ^ ((r0 >> 1) & 3);
    const short* asrch = ahg + (size_t)(row0 + r0) * DDIM + p0 * 8;
    const short* asrcl = alg + (size_t)(row0 + r0) * DDIM + p0 * 8;
    const short* bsrch = ehg + (size_t)(col0 + r0) * DDIM + p0 * 8;
    const short* bsrcl = elg + (size_t)(col0 + r0) * DDIM + p0 * 8;
    const int d0 = t * 8;                         // linear LDS dest

    f32x4 acc[2][4];
#pragma unroll
    for (int i = 0; i < 2; ++i)
#pragma unroll
        for (int j = 0; j < 4; ++j) {
            acc[i][j][0] = 0.f; acc[i][j][1] = 0.f;
            acc[i][j][2] = 0.f; acc[i][j][3] = 0.f;
        }

#pragma unroll
    for (int ch = 0; ch < 8; ++ch) {
        __syncthreads();  // prior chunk's LDS reads complete
        gload_lds16(asrch + ch * 32, &Ah[d0]);
        gload_lds16(asrcl + ch * 32, &Al[d0]);
        gload_lds16(bsrch + ch * 32, &Bh[d0]);
        gload_lds16(bsrcl + ch * 32, &Bl[d0]);
        __syncthreads();  // drains vmcnt -> tiles visible

        bf16x8 ah[2], al[2];
#pragma unroll
        for (int i = 0; i < 2; ++i) {
            int off = (wm * 32 + i * 16 + n15) * 32 + ((quad ^ swz) * 8);
            ah[i] = *(const bf16x8*)&Ah[off];
            al[i] = *(const bf16x8*)&Al[off];
        }
#pragma unroll
        for (int j = 0; j < 4; ++j) {
            int boff = (wn * 64 + j * 16 + n15) * 32 + ((quad ^ swz) * 8);
            bf16x8 bh = *(const bf16x8*)&Bh[boff];
            bf16x8 bl = *(const bf16x8*)&Bl[boff];
#pragma unroll
            for (int i = 0; i < 2; ++i) {
                acc[i][j] = __builtin_amdgcn_mfma_f32_16x16x32_bf16(ah[i], bh, acc[i][j], 0, 0, 0);
                acc[i][j] = __builtin_amdgcn_mfma_f32_16x16x32_bf16(ah[i], bl, acc[i][j], 0, 0, 0);
                acc[i][j] = __builtin_amdgcn_mfma_f32_16x16x32_bf16(al[i], bh, acc[i][j], 0, 0, 0);
            }
        }
    }

    // ---- epilogue: per-wave top-2 over its 64 codes (R4 semantics) ----
    float esqv[4];
#pragma unroll
    for (int j = 0; j < 4; ++j) esqv[j] = esq[col0 + wn * 64 + j * 16 + n15];

#pragma unroll
    for (int i = 0; i < 2; ++i) {
#pragma unroll
        for (int reg = 0; reg < 4; ++reg) {
            float m1 = FLT_MAX, m2 = FLT_MAX;
            int bi = 0;
#pragma unroll
            for (int j = 0; j < 4; ++j) {
                float d = esqv[j] - 2.0f * acc[i][j][reg];
                int code = col0 + wn * 64 + j * 16 + n15;
                if (d < m1) { m2 = m1; m1 = d; bi = code; }
                else if (d < m2) { m2 = d; }
            }
#pragma unroll
            for (int off = 1; off < 16; off <<= 1) {
                float om1 = __shfl_xor(m1, off);
                float om2 = __shfl_xor(m2, off);
                int obi = __shfl_xor(bi, off);
                bool take = (om1 < m1) || (om1 == m1 && obi < bi);
                if (take) { m2 = fminf(m1, om2); m1 = om1; bi = obi; }
                else      { m2 = fminf(om1, m2); }
            }
            if (n15 == 0) {
                int rg = (int)row0 + wm * 32 + i * 16 + quad * 4 + reg;
                int slot = ni * 2 + wn;
                pmin2[(size_t)slot * NROWS + rg] = make_float2(m1, m2);
                pidx[(size_t)slot * NROWS + rg] = bi;
            }
        }
    }
}

// ---- fallback GEMM (R6 verbatim): in-kernel A conversion, small ws ----
__global__ __launch_bounds__(256, 2) void vq_gemm_fb(const float* __restrict__ inp,
                                                     const short* __restrict__ ehg,
                                                     const short* __restrict__ elg,
                                                     const float* __restrict__ esq,
                                                     float2* __restrict__ pmin2,
                                                     int* __restrict__ pidx) {
    __shared__ __align__(16) short Ah[128 * 32];
    __shared__ __align__(16) short Al[128 * 32];
    __shared__ __align__(16) short Bh[128 * 32];
    __shared__ __align__(16) short Bl[128 * 32];

    const int t = threadIdx.x;
    const int mi = blockIdx.x >> 5, ni = blockIdx.x & 31;
    const size_t row0 = (size_t)mi * 128;
    const int col0 = ni * 128;
    const int lane = t & 63, wave = t >> 6;
    const int wm = wave >> 1, wn = wave & 1;
    const int n15 = lane & 15, quad = lane >> 4;
    const int swz = (n15 >> 1) & 3;

    const int ar0 = t >> 2, ac0 = t & 3;
    const int ap0 = ac0 ^ ((ar0 >> 1) & 3);
    const int ar1 = (t + 256) >> 2, ac1 = ac0;
    const int ap1 = ac1 ^ ((ar1 >> 1) & 3);
    const float* asrc0 = inp + (row0 + ar0) * DDIM + ac0 * 8;
    const float* asrc1 = inp + (row0 + ar1) * DDIM + ac1 * 8;
    short* adst0h = &Ah[ar0 * 32 + ap0 * 8];
    short* adst0l = &Al[ar0 * 32 + ap0 * 8];
    short* adst1h = &Ah[ar1 * 32 + ap1 * 8];
    short* adst1l = &Al[ar1 * 32 + ap1 * 8];
    const int br0 = ar0, bp0 = ac0, bk0 = bp0 ^ ((br0 >> 1) & 3);
    const int br1 = ar1, bp1 = ac1, bk1 = bp1 ^ ((br1 >> 1) & 3);
    const short* bsrc0h = ehg + (size_t)(col0 + br0) * DDIM + bk0 * 8;
    const short* bsrc0l = elg + (size_t)(col0 + br0) * DDIM + bk0 * 8;
    const short* bsrc1h = ehg + (size_t)(col0 + br1) * DDIM + bk1 * 8;
    const short* bsrc1l = elg + (size_t)(col0 + br1) * DDIM + bk1 * 8;

    f32x4 acc[4][4];
#pragma unroll
    for (int i = 0; i < 4; ++i)
#pragma unroll
        for (int j = 0; j < 4; ++j) {
            acc[i][j][0] = 0.f; acc[i][j][1] = 0.f;
            acc[i][j][2] = 0.f; acc[i][j][3] = 0.f;
        }

#pragma unroll
    for (int ch = 0; ch < 8; ++ch) {
        __syncthreads();
        gload_lds16(bsrc0h + ch * 32, &Bh[t * 8]);
        gload_lds16(bsrc0l + ch * 32, &Bl[t * 8]);
        gload_lds16(bsrc1h + ch * 32, &Bh[(t + 256) * 8]);
        gload_lds16(bsrc1l + ch * 32, &Bl[(t + 256) * 8]);
        stage8(asrc0 + ch * 32, adst0h, adst0l);
        stage8(asrc1 + ch * 32, adst1h, adst1l);
        __syncthreads();

        bf16x8 ah[4], al[4];
#pragma unroll
        for (int i = 0; i < 4; ++i) {
            int off = (wm * 64 + i * 16 + n15) * 32 + ((quad ^ swz) * 8);
            ah[i] = *(const bf16x8*)&Ah[off];
            al[i] = *(const bf16x8*)&Al[off];
        }
#pragma unroll
        for (int j = 0; j < 4; ++j) {
            int boff = (wn * 64 + j * 16 + n15) * 32 + ((quad ^ swz) * 8);
            bf16x8 bh = *(const bf16x8*)&Bh[boff];
            bf16x8 bl = *(const bf16x8*)&Bl[boff];
#pragma unroll
            for (int i = 0; i < 4; ++i) {
                acc[i][j] = __builtin_amdgcn_mfma_f32_16x16x32_bf16(ah[i], bh, acc[i][j], 0, 0, 0);
                acc[i][j] = __builtin_amdgcn_mfma_f32_16x16x32_bf16(ah[i], bl, acc[i][j], 0, 0, 0);
                acc[i][j] = __builtin_amdgcn_mfma_f32_16x16x32_bf16(al[i], bh, acc[i][j], 0, 0, 0);
            }
        }
    }

    float esqv[4];
#pragma unroll
    for (int j = 0; j < 4; ++j) esqv[j] = esq[col0 + wn * 64 + j * 16 + n15];

#pragma unroll
    for (int i = 0; i < 4; ++i) {
#pragma unroll
        for (int reg = 0; reg < 4; ++reg) {
            float m1 = FLT_MAX, m2 = FLT_MAX;
            int bi = 0;
#pragma unroll
            for (int j = 0; j < 4; ++j) {
                float d = esqv[j] - 2.0f * acc[i][j][reg];
                int code = col0 + wn * 64 + j * 16 + n15;
                if (d < m1) { m2 = m1; m1 = d; bi = code; }
                else if (d < m2) { m2 = d; }
            }
#pragma unroll
            for (int off = 1; off < 16; off <<= 1) {
                float om1 = __shfl_xor(m1, off);
                float om2 = __shfl_xor(m2, off);
                int obi = __shfl_xor(bi, off);
                bool take = (om1 < m1) || (om1 == m1 && obi < bi);
                if (take) { m2 = fminf(m1, om2); m1 = om1; bi = obi; }
                else      { m2 = fminf(om1, m2); }
            }
            if (n15 == 0) {
                int rg = (int)row0 + wm * 64 + i * 16 + quad * 4 + reg;
                int slot = ni * 2 + wn;
                pmin2[(size_t)slot * NROWS + rg] = make_float2(m1, m2);
                pidx[(size_t)slot * NROWS + rg] = bi;
            }
        }
    }
}

// ---- reduce 64 per-wave partials per row; flag near-ties (+key init) ----
__global__ __launch_bounds__(256) void vq_reduce(const float2* __restrict__ pmin2,
                                                 const int* __restrict__ pidx,
                                                 int* __restrict__ idx_final,
                                                 int* __restrict__ flags,
                                                 int* __restrict__ fcount,
                                                 unsigned long long* __restrict__ keys) {
    int row = blockIdx.x * 256 + threadIdx.x;
    float m1 = FLT_MAX, m2 = FLT_MAX;
    int bi = 0;
    for (int nb = 0; nb < NSLOT; ++nb) {
        float2 p = pmin2[(size_t)nb * NROWS + row];
        int pi = pidx[(size_t)nb * NROWS + row];
        if (p.x < m1) { m2 = fminf(m1, p.y); m1 = p.x; bi = pi; }
        else          { m2 = fminf(m2, p.x); }
    }
    idx_final[row] = bi;
    if (m2 - m1 < GAP_THRESH) {
        int s = atomicAdd(fcount, 1);
        flags[s] = row;
        if (keys) keys[s] = 0xFFFFFFFFFFFFFFFFull;
    }
}

// ---- fast fp32 recheck: 16 blocks per flagged row, 1 code/thread ----
// d computed in the EXACT order of the original recheck (bit-identical);
// reduction is pure min over sortable keys -> order-independent, exact
// old tie rule (min d, tie -> lowest code index).
__global__ __launch_bounds__(256) void vq_recheck2(const float* __restrict__ inp,
                                                   const float* __restrict__ emb,
                                                   const float* __restrict__ esq,
                                                   const int* __restrict__ flags,
                                                   const int* __restrict__ fcount,
                                                   unsigned long long* __restrict__ keys) {
    __shared__ float4 xs[64];
    __shared__ unsigned long long wbest[4];
    const int t = threadIdx.x;
    const int total = (*fcount) * 16;
    for (int wi = blockIdx.x; wi < total; wi += gridDim.x) {
        const int fi = wi >> 4, cb = wi & 15;
        const int row = flags[fi];
        __syncthreads();
        if (t < 64) xs[t] = ((const float4*)inp)[(size_t)row * 64 + t];
        __syncthreads();
        const int c = cb * 256 + t;
        const float4* e4 = (const float4*)emb + (size_t)c * 64;
        float dot = 0.f;
        for (int d4 = 0; d4 < 64; ++d4) {
            float4 e = e4[d4];
            float4 x = xs[d4];
            dot += e.x * x.x; dot += e.y * x.y;
            dot += e.z * x.z; dot += e.w * x.w;
        }
        float d = esq[c] - 2.0f * dot;
        unsigned u = __float_as_uint(d);
        unsigned skey = (u & 0x80000000u) ? ~u : (u | 0x80000000u);
        unsigned long long k = ((unsigned long long)skey << 32) | (unsigned)c;
#pragma unroll
        for (int off = 1; off < 64; off <<= 1) {
            unsigned long long o = __shfl_xor(k, off);
            if (o < k) k = o;
        }
        if ((t & 63) == 0) wbest[t >> 6] = k;
        __syncthreads();
        if (t == 0) {
            unsigned long long b = wbest[0];
            if (wbest[1] < b) b = wbest[1];
            if (wbest[2] < b) b = wbest[2];
            if (wbest[3] < b) b = wbest[3];
            atomicMin(&keys[fi], b);
        }
    }
}

__global__ __launch_bounds__(256) void vq_unpack(const int* __restrict__ flags,
                                                 const int* __restrict__ fcount,
                                                 const unsigned long long* __restrict__ keys,
                                                 int* __restrict__ idx_final) {
    int i = blockIdx.x * 256 + threadIdx.x;
    if (i < *fcount) idx_final[flags[i]] = (int)(keys[i] & 0xFFFFFFFFull);
}

// ---- original serial recheck (fallback path only) ----
__global__ __launch_bounds__(256) void vq_recheck(const float* __restrict__ inp,
                                                  const float* __restrict__ emb,
                                                  const float* __restrict__ esq,
                                                  const int* __restrict__ flags,
                                                  const int* __restrict__ fcount,
                                                  int* __restrict__ idx_final) {
    __shared__ float4 xs[64];
    __shared__ float sv[4];
    __shared__ int si[4];
    const int t = threadIdx.x;
    const int cnt = *fcount;
    for (int f = blockIdx.x; f < cnt; f += gridDim.x) {
        int row = flags[f];
        __syncthreads();
        if (t < 64) xs[t] = ((const float4*)inp)[(size_t)row * 64 + t];
        __syncthreads();
        float m1 = FLT_MAX;
        int bi = 0x7FFFFFFF;
        for (int cc = 0; cc < 16; ++cc) {
            int c = cc * 256 + t;
            const float4* e4 = (const float4*)emb + (size_t)c * 64;
            float dot = 0.f;
            for (int d4 = 0; d4 < 64; ++d4) {
                float4 e = e4[d4];
                float4 x = xs[d4];
                dot += e.x * x.x; dot += e.y * x.y;
                dot += e.z * x.z; dot += e.w * x.w;
            }
            float d = esq[c] - 2.0f * dot;
            if (d < m1 || (d == m1 && c < bi)) { m1 = d; bi = c; }
        }
#pragma unroll
        for (int off = 1; off < 64; off <<= 1) {
            float om = __shfl_xor(m1, off);
            int ob = __shfl_xor(bi, off);
            if (om < m1 || (om == m1 && ob < bi)) { m1 = om; bi = ob; }
        }
        if ((t & 63) == 0) { sv[t >> 6] = m1; si[t >> 6] = bi; }
        __syncthreads();
        if (t == 0) {
            for (int w = 1; w < 4; ++w)
                if (sv[w] < m1 || (sv[w] == m1 && si[w] < bi)) { m1 = sv[w]; bi = si[w]; }
            idx_final[row] = bi;
        }
    }
}

// ---- gather quantized, write indices, per-block loss partial ----
__global__ __launch_bounds__(256) void vq_gather(const float* __restrict__ inp,
                                                 const float* __restrict__ emb,
                                                 const int* __restrict__ idx_final,
                                                 float* __restrict__ out,
                                                 float* __restrict__ loss_part) {
    __shared__ float wsum[4];
    size_t gid = (size_t)blockIdx.x * 256 + threadIdx.x;
    int row = (int)(gid >> 6), c4 = (int)(gid & 63);
    int k = idx_final[row];
    float4 e = ((const float4*)emb)[(size_t)k * 64 + c4];
    float4 x = ((const float4*)inp)[gid];
    ((float4*)out)[gid] = e;
    float dx = e.x - x.x, dy = e.y - x.y, dz = e.z - x.z, dw = e.w - x.w;
    float ls = dx * dx + dy * dy + dz * dz + dw * dw;
#pragma unroll
    for (int off = 32; off >= 1; off >>= 1) ls += __shfl_down(ls, off);
    if ((threadIdx.x & 63) == 0) wsum[threadIdx.x >> 6] = ls;
    if (c4 == 0) out[(size_t)QSIZE + 1 + row] = (float)k;
    __syncthreads();
    if (threadIdx.x == 0)
        loss_part[blockIdx.x] = wsum[0] + wsum[1] + wsum[2] + wsum[3];
}

__global__ __launch_bounds__(256) void loss_kernel(const float* __restrict__ loss_part,
                                                   float* __restrict__ out) {
    __shared__ float sw[4];
    int t = threadIdx.x;
    float s = 0.0f;
    for (int i = t; i < NLBLK; i += 256) s += loss_part[i];
#pragma unroll
    for (int off = 32; off >= 1; off >>= 1) s += __shfl_down(s, off);
    if ((t & 63) == 0) sw[t >> 6] = s;
    __syncthreads();
    if (t == 0)
        out[QSIZE] = (sw[0] + sw[1] + sw[2] + sw[3]) * (1.0f / 16777216.0f);
}

extern "C" void kernel_launch(void* const* d_in, const int* in_sizes, int n_in,
                              void* d_out, int out_size, void* d_ws, size_t ws_size,
                              hipStream_t stream) {
    const float* inp = (const float*)d_in[0];
    const float* emb = (const float*)d_in[1];
    float* out = (float*)d_out;
    float* ws = (float*)d_ws;

    float* esq = ws;
    int* fcount = (int*)ws + O_FCOUNT;
    int* flags = (int*)ws + O_FLAGS;
    int* idx_final = (int*)ws + O_IDXF;
    float* loss_part = ws + O_LPART;
    short* eh = (short*)(ws + O_EMBH);
    short* el = (short*)(ws + O_EMBL);

    // partials in d_out's quantized region (overwritten by vq_gather)
    float2* pmin2 = (float2*)out;                 // [0, 8388608) floats
    int* pidx = (int*)out + 8388608;              // [8388608, 12582912)

    hipLaunchKernelGGL(esq_conv, dim3(KCODES), dim3(64), 0, stream, emb, ws, eh, el);

    if (ws_size >= WS_NEED_FLOATS * 4ull) {
        short* ah = (short*)(ws + O_AH);
        short* al = (short*)(ws + O_AL);
        unsigned long long* keys = (unsigned long long*)(ws + O_KEYS);
        hipLaunchKernelGGL(inp_conv, dim3(8192), dim3(256), 0, stream, inp, ah, al);
        hipLaunchKernelGGL(vq_gemm, dim3((NROWS / 128) * 32), dim3(512), 0, stream,
                           ah, al, eh, el, esq, pmin2, pidx);
        hipLaunchKernelGGL(vq_reduce, dim3(NROWS / 256), dim3(256), 0, stream,
                           pmin2, pidx, idx_final, flags, fcount, keys);
        hipLaunchKernelGGL(vq_recheck2, dim3(8192), dim3(256), 0, stream,
                           inp, emb, esq, flags, fcount, keys);
        hipLaunchKernelGGL(vq_unpack, dim3(NROWS / 256), dim3(256), 0, stream,
                           flags, fcount, keys, idx_final);
    } else {
        hipLaunchKernelGGL(vq_gemm_fb, dim3((NROWS / 128) * 32), dim3(256), 0, stream,
                           inp, eh, el, esq, pmin2, pidx);
        hipLaunchKernelGGL(vq_reduce, dim3(NROWS / 256), dim3(256), 0, stream,
                           pmin2, pidx, idx_final, flags, fcount,
                           (unsigned long long*)nullptr);
        hipLaunchKernelGGL(vq_recheck, dim3(256), dim3(256), 0, stream,
                           inp, emb, esq, flags, fcount, idx_final);
    }

    hipLaunchKernelGGL(vq_gather, dim3(NLBLK), dim3(256), 0, stream,
                       inp, emb, idx_final, out, loss_part);
    hipLaunchKernelGGL(loss_kernel, dim3(1), dim3(256), 0, stream, loss_part, out);
}